// Round 27
// baseline (586.451 us; speedup 1.0000x reference)
//
#include <hip/hip_runtime.h>
#include <math.h>

// ---------------- constants ----------------
#define EE 128
#define DI 256
#define HH 8
#define PP 32
#define NN 64
#define DC 4
#define XBC 384
#define DIN 648
#define NL 4
#define LSEQ 256
#define BB 256
#define TTOK (BB * LSEQ)   // 65536 tokens
#define EPSF 1e-5f

typedef __attribute__((ext_vector_type(8))) short short8;
typedef __attribute__((ext_vector_type(4))) float f32x4;

__device__ inline short f2bf(float f) {
  unsigned u = __builtin_bit_cast(unsigned, f);
  u += 0x7fff + ((u >> 16) & 1);   // RNE
  return (short)(u >> 16);
}
__device__ inline float bf2f(unsigned short u) {
  unsigned x = ((unsigned)u) << 16;
  return __builtin_bit_cast(float, x);
}
// silu via v_rcp_f32 (<=1 ulp; exact div is a ~15-inst sequence on gfx950)
__device__ inline float fast_silu(float a) {
  return a * __builtin_amdgcn_rcpf(1.f + __expf(-a));
}

// ---------------- one-shot weight conversion fp32 -> bf16 ----------------
__global__ __launch_bounds__(256) void cvt_w_kernel(
    const float* __restrict__ in_w, const float* __restrict__ ow,
    unsigned short* __restrict__ in_wb, unsigned short* __restrict__ owb) {
  int i = blockIdx.x * 256 + threadIdx.x;   // grid covers NL*DIN*EE = 331776
  in_wb[i] = (unsigned short)f2bf(in_w[i]);
  if (i < NL * EE * DI) owb[i] = (unsigned short)f2bf(ow[i]);
}

// ---------------- in-proj GEMM (K=128, N=640 full tiles): single-shot staging ----------------
// grid = dim3(5, 512): all tiles full, no guards. dt handled by dt_kernel.
__global__ __launch_bounds__(256) void gemm_in_proj(
    const unsigned short* __restrict__ A, const unsigned short* __restrict__ B,
    unsigned short* __restrict__ Czx) {
  __shared__ __align__(16) unsigned short As[128][136];   // full A tile (K=128)
  __shared__ __align__(16) unsigned short Bs[128][136];   // full B tile
  const int tid = threadIdx.x;
  const int lane = tid & 63, wid = tid >> 6;
  const int wm = wid >> 1, wn = wid & 1;
  const int m0 = blockIdx.y * 128, n0 = blockIdx.x * 128;
  const int r = tid >> 1, hf = tid & 1;
  const int lr = lane & 15, lk = (lane >> 4) * 8;
  // ---- single-shot staging: whole 128x128 A and B tiles ----
  {
    const unsigned short* ap = A + (size_t)(m0 + r) * 128 + hf * 64;
#pragma unroll
    for (int v = 0; v < 8; ++v)
      *(short8*)&As[r][hf * 64 + v * 8] = *(const short8*)(ap + v * 8);
    const unsigned short* bp = B + (size_t)(n0 + r) * 128 + hf * 64;
#pragma unroll
    for (int v = 0; v < 8; ++v)
      *(short8*)&Bs[r][hf * 64 + v * 8] = *(const short8*)(bp + v * 8);
  }
  __syncthreads();
  // ---- all 4 K-steps, no barriers ----
  f32x4 acc[4][4] = {};
#pragma unroll
  for (int ks = 0; ks < 4; ++ks) {
    int k0 = ks * 32;
    short8 af[4], bfr[4];
#pragma unroll
    for (int mi = 0; mi < 4; ++mi) af[mi] = *(const short8*)&As[wm * 64 + mi * 16 + lr][k0 + lk];
#pragma unroll
    for (int ni = 0; ni < 4; ++ni) bfr[ni] = *(const short8*)&Bs[wn * 64 + ni * 16 + lr][k0 + lk];
#pragma unroll
    for (int mi = 0; mi < 4; ++mi)
#pragma unroll
      for (int ni = 0; ni < 4; ++ni)
        acc[mi][ni] = __builtin_amdgcn_mfma_f32_16x16x32_bf16(af[mi], bfr[ni], acc[mi][ni], 0, 0, 0);
  }
  __syncthreads();   // all LDS reads done; reuse As region as Vt
  {
    unsigned short (*Vt)[136] = (unsigned short(*)[136])&As[0][0];
#pragma unroll
    for (int mi = 0; mi < 4; ++mi) {
#pragma unroll
      for (int ni = 0; ni < 4; ++ni) {
        int row0 = wm * 64 + mi * 16 + (lane >> 4) * 4;
        int col = wn * 64 + ni * 16 + lr;
#pragma unroll
        for (int j = 0; j < 4; ++j)
          Vt[row0 + j][col] = (unsigned short)f2bf(acc[mi][ni][j]);
      }
    }
    __syncthreads();
    const int row = tid >> 4, cs = (tid & 15) * 8;
#pragma unroll
    for (int it = 0; it < 8; ++it) {
      int rr2 = it * 16 + row;
      *(uint4*)(Czx + (size_t)(m0 + rr2) * DIN + n0 + cs) = *(const uint4*)&Vt[rr2][cs];
    }
  }
}

// ---------------- dt GEMV: dtraw[t][h] = dot(tnb[t][:], Wdt[h][:]), fp32 accum ----------------
// grid = 256, block = 256: one thread per token; Wdt staged to LDS as fp32.
__global__ __launch_bounds__(256) void dt_kernel(
    const unsigned short* __restrict__ A,    // tnb bf16 [T][128]
    const unsigned short* __restrict__ Wdt,  // [8][128] bf16 (in_wb rows 640..647)
    float* __restrict__ dtraw) {             // [T][8]
  __shared__ float W[8][128];
  const int tid = threadIdx.x;
  {
    int base = tid * 4;   // 256*4 = 1024 elems
    ushort4 u = *(const ushort4*)(Wdt + base);
    float* wp = &W[0][0] + base;
    wp[0] = bf2f(u.x); wp[1] = bf2f(u.y); wp[2] = bf2f(u.z); wp[3] = bf2f(u.w);
  }
  __syncthreads();
  size_t token = (size_t)blockIdx.x * 256 + tid;
  const unsigned short* ap = A + token * 128;
  float acc[8] = {};
#pragma unroll
  for (int k0 = 0; k0 < 128; k0 += 8) {
    short8 a8 = *(const short8*)(ap + k0);
    float af[8];
#pragma unroll
    for (int j = 0; j < 8; ++j) af[j] = bf2f((unsigned short)a8[j]);
#pragma unroll
    for (int h = 0; h < 8; ++h) {
      float4 w0 = *(const float4*)&W[h][k0];
      float4 w1 = *(const float4*)&W[h][k0 + 4];
      acc[h] += af[0] * w0.x + af[1] * w0.y + af[2] * w0.z + af[3] * w0.w
              + af[4] * w1.x + af[5] * w1.y + af[6] * w1.z + af[7] * w1.w;
    }
  }
#pragma unroll
  for (int h = 0; h < 8; ++h) dtraw[token * 8 + h] = acc[h];
}

// ---------------- fused gate+RMS + out-proj + bf16 residual + next-LN ----------------
__global__ __launch_bounds__(256) void gemm_out_fused_ln(
    const unsigned short* __restrict__ ysc, const unsigned short* __restrict__ zx,
    const float* __restrict__ nw, const unsigned short* __restrict__ B,
    unsigned short* __restrict__ tres, const float* __restrict__ lnw,
    const float* __restrict__ lnb, unsigned* __restrict__ tnb) {
  __shared__ short As[128][40];
  __shared__ short Bs[128][40];
  __shared__ unsigned short Vt[128][136];
  __shared__ float rs_g[128], mu_s[128], rs_s[128];
  const int tid = threadIdx.x;
  const int lane = tid & 63, wid = tid >> 6;
  const int wm = wid >> 1, wn = wid & 1;
  const int m0 = blockIdx.x * 128;
  const int r = tid >> 1, hf = tid & 1;
  const int lr = lane & 15, lk = (lane >> 4) * 8;
  f32x4 acc[4][4] = {};
  float ssg = 0.f;
  for (int k0 = 0; k0 < 256; k0 += 32) {
    // stage A: gate on the fly
    {
      int col = k0 + hf * 16;
      const unsigned short* yp = ysc + (size_t)(m0 + r) * DI + col;
      const unsigned short* zp = zx + (size_t)(m0 + r) * DIN + col;
      short8 y0 = *(const short8*)(yp);
      short8 y1 = *(const short8*)(yp + 8);
      short8 z0 = *(const short8*)(zp);
      short8 z1 = *(const short8*)(zp + 8);
      float4 nw0 = *(const float4*)(nw + col);
      float4 nw1 = *(const float4*)(nw + col + 4);
      float4 nw2 = *(const float4*)(nw + col + 8);
      float4 nw3 = *(const float4*)(nw + col + 12);
      float nwv[16] = {nw0.x, nw0.y, nw0.z, nw0.w, nw1.x, nw1.y, nw1.z, nw1.w,
                       nw2.x, nw2.y, nw2.z, nw2.w, nw3.x, nw3.y, nw3.z, nw3.w};
      short8 a0, a1;
#pragma unroll
      for (int j = 0; j < 8; ++j) {
        float y = bf2f((unsigned short)y0[j]);
        float z = bf2f((unsigned short)z0[j]);
        float g = y * fast_silu(z);
        ssg += g * g;
        a0[j] = f2bf(g * nwv[j]);
        float y2 = bf2f((unsigned short)y1[j]);
        float z2 = bf2f((unsigned short)z1[j]);
        float g2 = y2 * fast_silu(z2);
        ssg += g2 * g2;
        a1[j] = f2bf(g2 * nwv[8 + j]);
      }
      *(short8*)&As[r][hf * 16] = a0;
      *(short8*)&As[r][hf * 16 + 8] = a1;
    }
    {
      const unsigned short* bp = B + (size_t)r * 256 + k0 + hf * 16;
      *(short8*)&Bs[r][hf * 16] = *(const short8*)(bp);
      *(short8*)&Bs[r][hf * 16 + 8] = *(const short8*)(bp + 8);
    }
    __syncthreads();
    short8 af[4], bfr[4];
#pragma unroll
    for (int mi = 0; mi < 4; ++mi) af[mi] = *(const short8*)&As[wm * 64 + mi * 16 + lr][lk];
#pragma unroll
    for (int ni = 0; ni < 4; ++ni) bfr[ni] = *(const short8*)&Bs[wn * 64 + ni * 16 + lr][lk];
#pragma unroll
    for (int mi = 0; mi < 4; ++mi)
#pragma unroll
      for (int ni = 0; ni < 4; ++ni)
        acc[mi][ni] = __builtin_amdgcn_mfma_f32_16x16x32_bf16(af[mi], bfr[ni], acc[mi][ni], 0, 0, 0);
    __syncthreads();
  }
  // complete row rms: two threads per row
  ssg += __shfl_xor(ssg, 1);
  if (hf == 0) rs_g[r] = rsqrtf(ssg * (1.f / 256.f) + EPSF);
  __syncthreads();
  // epilogue: rms scale + bf16 residual add/store, bf16 LDS tile
#pragma unroll
  for (int mi = 0; mi < 4; ++mi) {
#pragma unroll
    for (int ni = 0; ni < 4; ++ni) {
      int row0 = wm * 64 + mi * 16 + (lane >> 4) * 4;
      int col = wn * 64 + ni * 16 + lr;
#pragma unroll
      for (int j = 0; j < 4; ++j) {
        int row = row0 + j;
        size_t idx = (size_t)(m0 + row) * 128 + col;
        float v = acc[mi][ni][j] * rs_g[row] + bf2f(tres[idx]);
        unsigned short us = (unsigned short)f2bf(v);
        tres[idx] = us;
        Vt[row][col] = us;
      }
    }
  }
  __syncthreads();
  // per-row LN stats (2 threads per row)
  {
    float s = 0.f, ss = 0.f;
#pragma unroll
    for (int kk = 0; kk < 8; ++kk) {
      short8 vv = *(const short8*)&Vt[r][hf * 64 + kk * 8];
#pragma unroll
      for (int j = 0; j < 8; ++j) {
        float f = bf2f((unsigned short)vv[j]);
        s += f; ss += f * f;
      }
    }
    s += __shfl_xor(s, 1);
    ss += __shfl_xor(ss, 1);
    if (hf == 0) {
      float mu = s * (1.f / 128.f);
      mu_s[r] = mu;
      rs_s[r] = rsqrtf(ss * (1.f / 128.f) - mu * mu + EPSF);
    }
  }
  __syncthreads();
  // LN write: packed bf16, coalesced
  float w0 = lnw[lane * 2], w1 = lnw[lane * 2 + 1];
  float b0 = lnb[lane * 2], b1 = lnb[lane * 2 + 1];
  for (int it = 0; it < 32; ++it) {
    int row = it * 4 + wid;
    float mu = mu_s[row], rr = rs_s[row];
    float v0 = bf2f(Vt[row][lane * 2]);
    float v1 = bf2f(Vt[row][lane * 2 + 1]);
    unsigned lo = (unsigned short)f2bf((v0 - mu) * rr * w0 + b0);
    unsigned hi = (unsigned short)f2bf((v1 - mu) * rr * w1 + b1);
    tnb[(size_t)(m0 + row) * 64 + lane] = lo | (hi << 16);
  }
}

// ---------------- patch-embed bf16 MFMA GEMM (bf16 out) ----------------
__global__ __launch_bounds__(256) void gemm_bf16_patch(
    const float* __restrict__ X, const float* __restrict__ B,
    const float* __restrict__ bias, unsigned short* __restrict__ C) {
  __shared__ short As[128][40];
  __shared__ short Bs[128][40];
  const int tid = threadIdx.x;
  const int lane = tid & 63, wid = tid >> 6;
  const int wm = wid >> 1, wn = wid & 1;
  const int m0 = blockIdx.x * 128;
  const int r = tid >> 1, hf = tid & 1;
  const int lr = lane & 15, lk = (lane >> 4) * 8;
  const int m = m0 + r;
  const int bb = m >> 8, px = (m >> 4) & 15, py = m & 15;
  f32x4 acc[4][4] = {};
  for (int k0 = 0; k0 < 768; k0 += 32) {
    int k = k0 + hf * 16;
    int c = k >> 8, dx = (k >> 4) & 15;
    {
      const float* ap = X + (((size_t)(bb * 3 + c) * 256 + px * 16 + dx) * 256 + py * 16);
      float4 v0 = *(const float4*)(ap + 0);
      float4 v1 = *(const float4*)(ap + 4);
      float4 v2 = *(const float4*)(ap + 8);
      float4 v3 = *(const float4*)(ap + 12);
      short8 s0, s1;
      s0[0] = f2bf(v0.x); s0[1] = f2bf(v0.y); s0[2] = f2bf(v0.z); s0[3] = f2bf(v0.w);
      s0[4] = f2bf(v1.x); s0[5] = f2bf(v1.y); s0[6] = f2bf(v1.z); s0[7] = f2bf(v1.w);
      s1[0] = f2bf(v2.x); s1[1] = f2bf(v2.y); s1[2] = f2bf(v2.z); s1[3] = f2bf(v2.w);
      s1[4] = f2bf(v3.x); s1[5] = f2bf(v3.y); s1[6] = f2bf(v3.z); s1[7] = f2bf(v3.w);
      *(short8*)&As[r][hf * 16] = s0;
      *(short8*)&As[r][hf * 16 + 8] = s1;
    }
    {
      const float* bp = B + (size_t)r * 768 + k;
      float4 v0 = *(const float4*)(bp + 0);
      float4 v1 = *(const float4*)(bp + 4);
      float4 v2 = *(const float4*)(bp + 8);
      float4 v3 = *(const float4*)(bp + 12);
      short8 s0, s1;
      s0[0] = f2bf(v0.x); s0[1] = f2bf(v0.y); s0[2] = f2bf(v0.z); s0[3] = f2bf(v0.w);
      s0[4] = f2bf(v1.x); s0[5] = f2bf(v1.y); s0[6] = f2bf(v1.z); s0[7] = f2bf(v1.w);
      s1[0] = f2bf(v2.x); s1[1] = f2bf(v2.y); s1[2] = f2bf(v2.z); s1[3] = f2bf(v2.w);
      s1[4] = f2bf(v3.x); s1[5] = f2bf(v3.y); s1[6] = f2bf(v3.z); s1[7] = f2bf(v3.w);
      *(short8*)&Bs[r][hf * 16] = s0;
      *(short8*)&Bs[r][hf * 16 + 8] = s1;
    }
    __syncthreads();
    short8 af[4], bfr[4];
#pragma unroll
    for (int mi = 0; mi < 4; ++mi) af[mi] = *(const short8*)&As[wm * 64 + mi * 16 + lr][lk];
#pragma unroll
    for (int ni = 0; ni < 4; ++ni) bfr[ni] = *(const short8*)&Bs[wn * 64 + ni * 16 + lr][lk];
#pragma unroll
    for (int mi = 0; mi < 4; ++mi)
#pragma unroll
      for (int ni = 0; ni < 4; ++ni)
        acc[mi][ni] = __builtin_amdgcn_mfma_f32_16x16x32_bf16(af[mi], bfr[ni], acc[mi][ni], 0, 0, 0);
    __syncthreads();
  }
#pragma unroll
  for (int mi = 0; mi < 4; ++mi) {
#pragma unroll
    for (int ni = 0; ni < 4; ++ni) {
      int row0 = m0 + wm * 64 + mi * 16 + (lane >> 4) * 4;
      int col = wn * 64 + ni * 16 + (lane & 15);
#pragma unroll
      for (int j = 0; j < 4; ++j)
        C[(size_t)(row0 + j) * 128 + col] = (unsigned short)f2bf(acc[mi][ni][j] + bias[col]);
    }
  }
}

// ---------------- fused pe-LN (bf16, in place) + block-0 LN (bf16 out) ----------------
__global__ __launch_bounds__(256) void ln_pe0_kernel(
    unsigned* t, unsigned* out,
    const float* __restrict__ pe_w, const float* __restrict__ pe_b,
    const float* __restrict__ l0w, const float* __restrict__ l0b) {
  int wid = threadIdx.x >> 6, lane = threadIdx.x & 63;
  size_t token = (size_t)blockIdx.x * 4 + wid;
  unsigned* p = t + token * 64;
  unsigned u = p[lane];
  float vx = bf2f((unsigned short)(u & 0xffff));
  float vy = bf2f((unsigned short)(u >> 16));
  // pe-LN
  float s = vx + vy;
#pragma unroll
  for (int off = 1; off < 64; off <<= 1) s += __shfl_xor(s, off);
  float mu = s * (1.f / 128.f);
  float dx = vx - mu, dy = vy - mu;
  float vs = dx * dx + dy * dy;
#pragma unroll
  for (int off = 1; off < 64; off <<= 1) vs += __shfl_xor(vs, off);
  float r = rsqrtf(vs * (1.f / 128.f) + EPSF);
  float t0 = dx * r * pe_w[lane * 2 + 0] + pe_b[lane * 2 + 0];
  float t1 = dy * r * pe_w[lane * 2 + 1] + pe_b[lane * 2 + 1];
  unsigned short s0 = (unsigned short)f2bf(t0);
  unsigned short s1 = (unsigned short)f2bf(t1);
  p[lane] = (unsigned)s0 | ((unsigned)s1 << 16);
  // block-0 LN on the STORED (rounded) residual values for consistency
  float r0 = bf2f(s0), r1 = bf2f(s1);
  float s2 = r0 + r1;
#pragma unroll
  for (int off = 1; off < 64; off <<= 1) s2 += __shfl_xor(s2, off);
  float mu2 = s2 * (1.f / 128.f);
  float d0 = r0 - mu2, d1 = r1 - mu2;
  float vs2 = d0 * d0 + d1 * d1;
#pragma unroll
  for (int off = 1; off < 64; off <<= 1) vs2 += __shfl_xor(vs2, off);
  float r2 = rsqrtf(vs2 * (1.f / 128.f) + EPSF);
  unsigned lo = (unsigned short)f2bf(d0 * r2 * l0w[lane * 2 + 0] + l0b[lane * 2 + 0]);
  unsigned hi = (unsigned short)f2bf(d1 * r2 * l0w[lane * 2 + 1] + l0b[lane * 2 + 1]);
  out[token * 64 + lane] = lo | (hi << 16);
}

// ---------------- chunked SSM scan, 4 heads/block; conv+dt fused; S shared 4-way ----------------
// grid = 512; b = bid&255, hq = bid>>8 (heads 4hq..4hq+3). 256 threads (4 waves).
// B/C conv+staging and S = C@B^T computed ONCE per block (shared by 4 heads).
// P computed in two sequential phases reusing Cb/Bb: phase A = heads 0,1; phase B = 2,3.
// Wave w owns head w's full h-update (32 rows).
__global__ __launch_bounds__(256, 2) void scan_chunk_kernel(
    const unsigned short* __restrict__ zx,   // [T][648] bf16 (cols 256.. = pre-conv xbc)
    const float* __restrict__ dtraw,         // [T][8] fp32
    const float* __restrict__ dtb,           // [8]
    const float* __restrict__ A_log,         // [8]
    const float* __restrict__ cw,            // [384][4] conv weights
    const float* __restrict__ cbv_g,         // [384] conv bias
    const float* __restrict__ Dp,            // [8]
    unsigned short* __restrict__ ysc) {      // [T][256] bf16
  const int b = blockIdx.x & 255, hq = blockIdx.x >> 8;
  const int h0 = hq * 4;
  const int tid = threadIdx.x;
  const int w = tid >> 6, lane = tid & 63;
  const int lr = lane & 15, lj = lane >> 4;
  __shared__ __align__(16) unsigned short Cb[64][72];    // C rows; P0 / P2 after bar2
  __shared__ __align__(16) unsigned short Bb[64][72];    // B rows; P1 / P3 after bar2
  __shared__ __align__(16) unsigned short BbT[64][72];   // [n][s]
  __shared__ __align__(16) unsigned short xT[4][32][72]; // per-head x [p][t]
  __shared__ __align__(16) unsigned short hbT[4][32][72];// per-head h [p][n]
  __shared__ float la[4][64], dtc[4][64], wt[4][64];
  for (int i = tid; i < 4608; i += 256) ((unsigned*)hbT)[i] = 0;
  f32x4 acc_h[8] = {};    // wave w: head w, rows rh*16.. (rh = frag>>2), cols ni*16..
  const float dp0 = Dp[h0], dp1 = Dp[h0 + 1], dp2 = Dp[h0 + 2], dp3 = Dp[h0 + 3];
  __syncthreads();

  for (int c = 0; c < 4; ++c) {
    const int tok0 = b * 256 + c * 64;
    // ---- dt + prefix-scan: wave w -> head h0+w ----
    {
      int hh = h0 + w;
      float raw = dtraw[(size_t)(tok0 + lane) * 8 + hh] + dtb[hh];
      float dt = raw > 20.f ? raw : log1pf(expf(raw));
      float v = -expf(A_log[hh]) * dt;
#pragma unroll
      for (int off = 1; off < 64; off <<= 1) {
        float u = __shfl_up(v, off);
        if (lane >= off) v += u;
      }
      la[w][lane] = v;
      dtc[w][lane] = dt;
    }
    // ---- staging with fused conv1d + SiLU: 256 x-items (4 heads) + 128 B + 128 C ----
    for (int it = tid; it < 512; it += 256) {
      int t0, ch, kind, sub;
      if (it < 256) {
        int hx = it >> 6, id = it & 63;
        t0 = (id >> 2) * 4; sub = (id & 3) * 8;
        ch = (h0 + hx) * 32 + sub; kind = hx;
      } else if (it < 384) {
        int id = it - 256;
        t0 = (id >> 3) * 4; sub = (id & 7) * 8;
        ch = 256 + sub; kind = 4;
      } else {
        int id = it - 384;
        t0 = (id >> 3) * 4; sub = (id & 7) * 8;
        ch = 320 + sub; kind = 5;
      }
      const unsigned short* zp = zx + (size_t)(tok0 + t0) * DIN + 256 + ch;
      const int t0loc = c * 64 + t0;
      short8 rr[7];
      if (t0loc >= 3) {
#pragma unroll
        for (int d = 0; d < 7; ++d)
          rr[d] = *(const short8*)(zp + (ptrdiff_t)(d - 3) * DIN);
      } else {
#pragma unroll
        for (int d = 0; d < 7; ++d) {
          short8 z8 = {};
          if (t0loc + d - 3 >= 0) z8 = *(const short8*)(zp + (ptrdiff_t)(d - 3) * DIN);
          rr[d] = z8;
        }
      }
      float4 cwv[8];
      float cbl[8];
#pragma unroll
      for (int j = 0; j < 8; ++j) {
        cwv[j] = *(const float4*)(cw + (ch + j) * 4);
        cbl[j] = cbv_g[ch + j];
      }
      short8 o[4];
#pragma unroll
      for (int tt = 0; tt < 4; ++tt) {
#pragma unroll
        for (int j = 0; j < 8; ++j) {
          float a = cbl[j]
                  + cwv[j].x * bf2f((unsigned short)rr[tt + 0][j])
                  + cwv[j].y * bf2f((unsigned short)rr[tt + 1][j])
                  + cwv[j].z * bf2f((unsigned short)rr[tt + 2][j])
                  + cwv[j].w * bf2f((unsigned short)rr[tt + 3][j]);
          o[tt][j] = f2bf(fast_silu(a));
        }
      }
      if (kind < 4) {
#pragma unroll
        for (int j = 0; j < 8; ++j) {
          ushort4 v;
          v.x = (unsigned short)o[0][j]; v.y = (unsigned short)o[1][j];
          v.z = (unsigned short)o[2][j]; v.w = (unsigned short)o[3][j];
          *(ushort4*)&xT[kind][sub + j][t0] = v;
        }
      } else if (kind == 4) {
        *(short8*)&Bb[t0 + 0][sub] = o[0];
        *(short8*)&Bb[t0 + 1][sub] = o[1];
        *(short8*)&Bb[t0 + 2][sub] = o[2];
        *(short8*)&Bb[t0 + 3][sub] = o[3];
#pragma unroll
        for (int j = 0; j < 8; ++j) {
          ushort4 v;
          v.x = (unsigned short)o[0][j]; v.y = (unsigned short)o[1][j];
          v.z = (unsigned short)o[2][j]; v.w = (unsigned short)o[3][j];
          *(ushort4*)&BbT[sub + j][t0] = v;
        }
      } else {
        *(short8*)&Cb[t0 + 0][sub] = o[0];
        *(short8*)&Cb[t0 + 1][sub] = o[1];
        *(short8*)&Cb[t0 + 2][sub] = o[2];
        *(short8*)&Cb[t0 + 3][sub] = o[3];
      }
    }
    __syncthreads();   // bar1
    wt[w][lane] = __expf(la[w][63] - la[w][lane]) * dtc[w][lane];   // own-wave use only
    // ---- phase1: S = C@B^T (shared), y_inter for 4 heads ----
    short8 afC0 = *(const short8*)&Cb[w * 16 + lr][lj * 8];
    short8 afC1 = *(const short8*)&Cb[w * 16 + lr][32 + lj * 8];
    f32x4 acc_s[4] = {};
#pragma unroll
    for (int ni = 0; ni < 4; ++ni) {
      short8 bf0 = *(const short8*)&Bb[ni * 16 + lr][lj * 8];
      short8 bf1 = *(const short8*)&Bb[ni * 16 + lr][32 + lj * 8];
      acc_s[ni] = __builtin_amdgcn_mfma_f32_16x16x32_bf16(afC0, bf0, acc_s[ni], 0, 0, 0);
      acc_s[ni] = __builtin_amdgcn_mfma_f32_16x16x32_bf16(afC1, bf1, acc_s[ni], 0, 0, 0);
    }
    f32x4 acc_y[4][2] = {};
#pragma unroll
    for (int hh = 0; hh < 4; ++hh) {
#pragma unroll
      for (int ni = 0; ni < 2; ++ni) {
        short8 hf0 = *(const short8*)&hbT[hh][ni * 16 + lr][lj * 8];
        short8 hf1 = *(const short8*)&hbT[hh][ni * 16 + lr][32 + lj * 8];
        acc_y[hh][ni] = __builtin_amdgcn_mfma_f32_16x16x32_bf16(afC0, hf0, acc_y[hh][ni], 0, 0, 0);
        acc_y[hh][ni] = __builtin_amdgcn_mfma_f32_16x16x32_bf16(afC1, hf1, acc_y[hh][ni], 0, 0, 0);
      }
    }
#pragma unroll
    for (int j = 0; j < 4; ++j) {
      int t = w * 16 + lj * 4 + j;
#pragma unroll
      for (int hh = 0; hh < 4; ++hh) {
        float at = __expf(la[hh][t]);
        acc_y[hh][0][j] *= at;
        acc_y[hh][1][j] *= at;
      }
    }
    // ---- h-update: wave w -> head w, full 32 rows (reads BbT, xT[w], wt[w]) ----
    {
      float aend = __expf(la[w][63]);
#pragma unroll
      for (int f = 0; f < 8; ++f)
#pragma unroll
        for (int j = 0; j < 4; ++j) acc_h[f][j] *= aend;
#pragma unroll
      for (int kk = 0; kk < 2; ++kk) {
#pragma unroll
        for (int rh = 0; rh < 2; ++rh) {
          short8 xv = *(const short8*)&xT[w][rh * 16 + lr][kk * 32 + lj * 8];
          short8 axf;
#pragma unroll
          for (int j = 0; j < 8; ++j)
            axf[j] = f2bf(bf2f((unsigned short)xv[j]) * wt[w][kk * 32 + lj * 8 + j]);
#pragma unroll
          for (int ni = 0; ni < 4; ++ni) {
            short8 bw = *(const short8*)&BbT[ni * 16 + lr][kk * 32 + lj * 8];
            acc_h[rh * 4 + ni] = __builtin_amdgcn_mfma_f32_16x16x32_bf16(axf, bw, acc_h[rh * 4 + ni], 0, 0, 0);
          }
        }
      }
    }
    __syncthreads();   // bar2: Cb/Bb row reads done
    // ---- P phase A: P0 -> Cb, P1 -> Bb ----
#pragma unroll
    for (int ni = 0; ni < 4; ++ni) {
      int s = ni * 16 + lr;
      float las0 = la[0][s], dts0 = dtc[0][s];
      float las1 = la[1][s], dts1 = dtc[1][s];
#pragma unroll
      for (int j = 0; j < 4; ++j) {
        int t = w * 16 + lj * 4 + j;
        float pv0 = 0.f, pv1 = 0.f;
        if (s <= t) {
          pv0 = acc_s[ni][j] * __expf(la[0][t] - las0) * dts0;
          pv1 = acc_s[ni][j] * __expf(la[1][t] - las1) * dts1;
        }
        Cb[t][s] = (unsigned short)f2bf(pv0);
        Bb[t][s] = (unsigned short)f2bf(pv1);
      }
    }
    __syncthreads();   // bar3
    // ---- PV A + y epilogue heads 0,1 ----
    {
      short8 aP0a = *(const short8*)&Cb[w * 16 + lr][lj * 8];
      short8 aP0b = *(const short8*)&Cb[w * 16 + lr][32 + lj * 8];
      short8 aP1a = *(const short8*)&Bb[w * 16 + lr][lj * 8];
      short8 aP1b = *(const short8*)&Bb[w * 16 + lr][32 + lj * 8];
#pragma unroll
      for (int ni = 0; ni < 2; ++ni) {
        short8 x0a = *(const short8*)&xT[0][ni * 16 + lr][lj * 8];
        short8 x0b = *(const short8*)&xT[0][ni * 16 + lr][32 + lj * 8];
        acc_y[0][ni] = __builtin_amdgcn_mfma_f32_16x16x32_bf16(aP0a, x0a, acc_y[0][ni], 0, 0, 0);
        acc_y[0][ni] = __builtin_amdgcn_mfma_f32_16x16x32_bf16(aP0b, x0b, acc_y[0][ni], 0, 0, 0);
        short8 x1a = *(const short8*)&xT[1][ni * 16 + lr][lj * 8];
        short8 x1b = *(const short8*)&xT[1][ni * 16 + lr][32 + lj * 8];
        acc_y[1][ni] = __builtin_amdgcn_mfma_f32_16x16x32_bf16(aP1a, x1a, acc_y[1][ni], 0, 0, 0);
        acc_y[1][ni] = __builtin_amdgcn_mfma_f32_16x16x32_bf16(aP1b, x1b, acc_y[1][ni], 0, 0, 0);
      }
#pragma unroll
      for (int ni = 0; ni < 2; ++ni) {
#pragma unroll
        for (int j = 0; j < 4; ++j) {
          int t = w * 16 + lj * 4 + j;
          int p = ni * 16 + lr;
          size_t base = (size_t)(tok0 + t) * DI;
          float yv0 = acc_y[0][ni][j] + dp0 * bf2f(xT[0][p][t]);
          ysc[base + (h0 + 0) * 32 + p] = (unsigned short)f2bf(yv0);
          float yv1 = acc_y[1][ni][j] + dp1 * bf2f(xT[1][p][t]);
          ysc[base + (h0 + 1) * 32 + p] = (unsigned short)f2bf(yv1);
        }
      }
    }
    __syncthreads();   // bar3b: P0/P1 reads done
    // ---- P phase B: P2 -> Cb, P3 -> Bb ----
#pragma unroll
    for (int ni = 0; ni < 4; ++ni) {
      int s = ni * 16 + lr;
      float las2 = la[2][s], dts2 = dtc[2][s];
      float las3 = la[3][s], dts3 = dtc[3][s];
#pragma unroll
      for (int j = 0; j < 4; ++j) {
        int t = w * 16 + lj * 4 + j;
        float pv2 = 0.f, pv3 = 0.f;
        if (s <= t) {
          pv2 = acc_s[ni][j] * __expf(la[2][t] - las2) * dts2;
          pv3 = acc_s[ni][j] * __expf(la[3][t] - las3) * dts3;
        }
        Cb[t][s] = (unsigned short)f2bf(pv2);
        Bb[t][s] = (unsigned short)f2bf(pv3);
      }
    }
    __syncthreads();   // bar3c
    // ---- PV B + y epilogue heads 2,3 ----
    {
      short8 aP2a = *(const short8*)&Cb[w * 16 + lr][lj * 8];
      short8 aP2b = *(const short8*)&Cb[w * 16 + lr][32 + lj * 8];
      short8 aP3a = *(const short8*)&Bb[w * 16 + lr][lj * 8];
      short8 aP3b = *(const short8*)&Bb[w * 16 + lr][32 + lj * 8];
#pragma unroll
      for (int ni = 0; ni < 2; ++ni) {
        short8 x2a = *(const short8*)&xT[2][ni * 16 + lr][lj * 8];
        short8 x2b = *(const short8*)&xT[2][ni * 16 + lr][32 + lj * 8];
        acc_y[2][ni] = __builtin_amdgcn_mfma_f32_16x16x32_bf16(aP2a, x2a, acc_y[2][ni], 0, 0, 0);
        acc_y[2][ni] = __builtin_amdgcn_mfma_f32_16x16x32_bf16(aP2b, x2b, acc_y[2][ni], 0, 0, 0);
        short8 x3a = *(const short8*)&xT[3][ni * 16 + lr][lj * 8];
        short8 x3b = *(const short8*)&xT[3][ni * 16 + lr][32 + lj * 8];
        acc_y[3][ni] = __builtin_amdgcn_mfma_f32_16x16x32_bf16(aP3a, x3a, acc_y[3][ni], 0, 0, 0);
        acc_y[3][ni] = __builtin_amdgcn_mfma_f32_16x16x32_bf16(aP3b, x3b, acc_y[3][ni], 0, 0, 0);
      }
#pragma unroll
      for (int ni = 0; ni < 2; ++ni) {
#pragma unroll
        for (int j = 0; j < 4; ++j) {
          int t = w * 16 + lj * 4 + j;
          int p = ni * 16 + lr;
          size_t base = (size_t)(tok0 + t) * DI;
          float yv2 = acc_y[2][ni][j] + dp2 * bf2f(xT[2][p][t]);
          ysc[base + (h0 + 2) * 32 + p] = (unsigned short)f2bf(yv2);
          float yv3 = acc_y[3][ni][j] + dp3 * bf2f(xT[3][p][t]);
          ysc[base + (h0 + 3) * 32 + p] = (unsigned short)f2bf(yv3);
        }
      }
    }
    // ---- h writeback: wave w -> hbT[w], 32 rows ----
#pragma unroll
    for (int rh = 0; rh < 2; ++rh)
#pragma unroll
      for (int ni = 0; ni < 4; ++ni)
#pragma unroll
        for (int j = 0; j < 4; ++j)
          hbT[w][rh * 16 + lj * 4 + j][ni * 16 + lr] = (unsigned short)f2bf(acc_h[rh * 4 + ni][j]);
    __syncthreads();   // bar4
  }
}

// ---------------- head: column mean + matmul + L2 normalize (fused) ----------------
__global__ __launch_bounds__(128) void head_kernel(
    const unsigned short* __restrict__ tn, const float* __restrict__ hw,
    const float* __restrict__ hb, float* __restrict__ out) {
  __shared__ float tm[128];
  __shared__ float red[2];
  int b = blockIdx.x, o = threadIdx.x;
  {
    const unsigned short* p = tn + (size_t)b * 256 * 128 + o;
    float acc = 0.f;
    for (int l = 0; l < 256; ++l) acc += bf2f(p[l * 128]);
    tm[o] = acc * (1.f / 256.f);
  }
  __syncthreads();
  float acc = hb[o];
  for (int e = 0; e < 128; ++e) acc += tm[e] * hw[o * 128 + e];
  float ss = acc * acc;
#pragma unroll
  for (int off = 1; off < 64; off <<= 1) ss += __shfl_xor(ss, off);
  if ((o & 63) == 0) red[o >> 6] = ss;
  __syncthreads();
  float nrm = fmaxf(sqrtf(red[0] + red[1]), 1e-12f);
  out[b * 128 + o] = acc / nrm;
}

extern "C" void kernel_launch(void* const* d_in, const int* in_sizes, int n_in,
                              void* d_out, int out_size, void* d_ws, size_t ws_size,
                              hipStream_t stream) {
  const float* x      = (const float*)d_in[0];
  const float* conv_w = (const float*)d_in[1];
  const float* conv_b = (const float*)d_in[2];
  const float* pe_w   = (const float*)d_in[3];
  const float* pe_b   = (const float*)d_in[4];
  const float* ln_w   = (const float*)d_in[5];
  const float* ln_b   = (const float*)d_in[6];
  const float* in_w   = (const float*)d_in[7];
  const float* c1w    = (const float*)d_in[8];
  const float* c1b    = (const float*)d_in[9];
  const float* dtb    = (const float*)d_in[10];
  const float* A_log  = (const float*)d_in[11];
  const float* Dp     = (const float*)d_in[12];
  const float* nw     = (const float*)d_in[13];
  const float* ow     = (const float*)d_in[14];
  const float* fn_w   = (const float*)d_in[15];
  const float* fn_b   = (const float*)d_in[16];
  const float* hw     = (const float*)d_in[17];
  const float* hb     = (const float*)d_in[18];
  float* out = (float*)d_out;

  const size_t T = TTOK;
  char* w8 = (char*)d_ws;
  unsigned short* t_buf = (unsigned short*)w8;   w8 += T * 128 * 2;   // residual bf16
  unsigned*       tnb   = (unsigned*)w8;         w8 += T * 128 * 2;   // ln out bf16
  unsigned short* zx    = (unsigned short*)w8;   w8 += T * (size_t)DIN * 2; // in-proj bf16
  float*          dtraw = (float*)w8;            w8 += T * 8 * 4;
  unsigned short* ysc   = (unsigned short*)w8;   w8 += T * (size_t)DI * 2;  // scan out bf16
  unsigned short* in_wb = (unsigned short*)w8;   w8 += (size_t)NL * DIN * EE * 2;
  unsigned short* owb   = (unsigned short*)w8;   w8 += (size_t)NL * EE * DI * 2;
  if ((size_t)(w8 - (char*)d_ws) > ws_size) return;  // workspace too small

  // one-shot weight conversion (NL*DIN*EE = 331776 = 1296*256)
  cvt_w_kernel<<<1296, 256, 0, stream>>>(in_w, ow, in_wb, owb);

  // patch embed + bias (bf16 residual), then fused pe-LN + block-0 LN
  gemm_bf16_patch<<<dim3(512, 1), 256, 0, stream>>>(x, conv_w, conv_b, t_buf);
  ln_pe0_kernel<<<16384, 256, 0, stream>>>((unsigned*)t_buf, tnb, pe_w, pe_b, ln_w, ln_b);

  for (int i = 0; i < NL; ++i) {
    gemm_in_proj<<<dim3(5, 512), 256, 0, stream>>>(
        (const unsigned short*)tnb, in_wb + (size_t)i * DIN * EE, zx);
    dt_kernel<<<256, 256, 0, stream>>>(
        (const unsigned short*)tnb, in_wb + (size_t)i * DIN * EE + 640 * 128, dtraw);
    scan_chunk_kernel<<<512, 256, 0, stream>>>(
        zx, dtraw, dtb + i * HH, A_log + i * HH,
        c1w + (size_t)i * XBC * DC, c1b + (size_t)i * XBC, Dp + i * HH, ysc);
    const float* nlw = (i < NL - 1) ? (ln_w + (i + 1) * 128) : fn_w;
    const float* nlb = (i < NL - 1) ? (ln_b + (i + 1) * 128) : fn_b;
    gemm_out_fused_ln<<<512, 256, 0, stream>>>(
        ysc, zx, nw + i * DI, owb + (size_t)i * EE * DI, t_buf, nlw, nlb, tnb);
  }

  // tnb holds final-LN output (fused in last gemm_out_fused_ln)
  head_kernel<<<256, 128, 0, stream>>>((const unsigned short*)tnb, hw, hb, out);
}

// Round 28
// 555.779 us; speedup vs baseline: 1.0552x; 1.0552x over previous
//
#include <hip/hip_runtime.h>
#include <math.h>

// ---------------- constants ----------------
#define EE 128
#define DI 256
#define HH 8
#define PP 32
#define NN 64
#define DC 4
#define XBC 384
#define DIN 648
#define NL 4
#define LSEQ 256
#define BB 256
#define TTOK (BB * LSEQ)   // 65536 tokens
#define EPSF 1e-5f

typedef __attribute__((ext_vector_type(8))) short short8;
typedef __attribute__((ext_vector_type(4))) float f32x4;

__device__ inline short f2bf(float f) {
  unsigned u = __builtin_bit_cast(unsigned, f);
  u += 0x7fff + ((u >> 16) & 1);   // RNE
  return (short)(u >> 16);
}
__device__ inline float bf2f(unsigned short u) {
  unsigned x = ((unsigned)u) << 16;
  return __builtin_bit_cast(float, x);
}
// silu via v_rcp_f32 (<=1 ulp; exact div is a ~15-inst sequence on gfx950)
__device__ inline float fast_silu(float a) {
  return a * __builtin_amdgcn_rcpf(1.f + __expf(-a));
}

// ---------------- one-shot weight conversion fp32 -> bf16 ----------------
__global__ __launch_bounds__(256) void cvt_w_kernel(
    const float* __restrict__ in_w, const float* __restrict__ ow,
    unsigned short* __restrict__ in_wb, unsigned short* __restrict__ owb) {
  int i = blockIdx.x * 256 + threadIdx.x;   // grid covers NL*DIN*EE = 331776
  in_wb[i] = (unsigned short)f2bf(in_w[i]);
  if (i < NL * EE * DI) owb[i] = (unsigned short)f2bf(ow[i]);
}

// ---------------- in-proj GEMM (K=128, N=640 full tiles): single-shot staging ----------------
// grid = dim3(5, 512). n0==0 blocks also compute dtraw = As @ Wdt^T (MFMA, 8 extra/wave)
// reusing the staged A tile — same summation chain as the old n0==640 side-channel.
__global__ __launch_bounds__(256) void gemm_in_proj(
    const unsigned short* __restrict__ A, const unsigned short* __restrict__ B,
    const unsigned short* __restrict__ Wdt,   // [8][128] bf16 (in_wb rows 640..647)
    unsigned short* __restrict__ Czx, float* __restrict__ dtraw) {
  __shared__ __align__(16) unsigned short As[128][136];   // full A tile (K=128)
  __shared__ __align__(16) unsigned short Bs[128][136];   // full B tile
  const int tid = threadIdx.x;
  const int lane = tid & 63, wid = tid >> 6;
  const int wm = wid >> 1, wn = wid & 1;
  const int m0 = blockIdx.y * 128, n0 = blockIdx.x * 128;
  const int r = tid >> 1, hf = tid & 1;
  const int lr = lane & 15, lk = (lane >> 4) * 8;
  // ---- single-shot staging: whole 128x128 A and B tiles ----
  {
    const unsigned short* ap = A + (size_t)(m0 + r) * 128 + hf * 64;
#pragma unroll
    for (int v = 0; v < 8; ++v)
      *(short8*)&As[r][hf * 64 + v * 8] = *(const short8*)(ap + v * 8);
    const unsigned short* bp = B + (size_t)(n0 + r) * 128 + hf * 64;
#pragma unroll
    for (int v = 0; v < 8; ++v)
      *(short8*)&Bs[r][hf * 64 + v * 8] = *(const short8*)(bp + v * 8);
  }
  __syncthreads();
  // ---- all 4 K-steps, no barriers ----
  f32x4 acc[4][4] = {};
#pragma unroll
  for (int ks = 0; ks < 4; ++ks) {
    int k0 = ks * 32;
    short8 af[4], bfr[4];
#pragma unroll
    for (int mi = 0; mi < 4; ++mi) af[mi] = *(const short8*)&As[wm * 64 + mi * 16 + lr][k0 + lk];
#pragma unroll
    for (int ni = 0; ni < 4; ++ni) bfr[ni] = *(const short8*)&Bs[wn * 64 + ni * 16 + lr][k0 + lk];
#pragma unroll
    for (int mi = 0; mi < 4; ++mi)
#pragma unroll
      for (int ni = 0; ni < 4; ++ni)
        acc[mi][ni] = __builtin_amdgcn_mfma_f32_16x16x32_bf16(af[mi], bfr[ni], acc[mi][ni], 0, 0, 0);
  }
  // ---- dt MFMA epilogue (n0==0 blocks): wave wid covers rows wid*32..wid*32+31 ----
  if (n0 == 0) {
    f32x4 accd[2] = {};
#pragma unroll
    for (int ks = 0; ks < 4; ++ks) {
      int k0 = ks * 32;
      short8 bw = {};
      if (lr < 8) bw = *(const short8*)(Wdt + (size_t)lr * 128 + k0 + lk);
#pragma unroll
      for (int f = 0; f < 2; ++f) {
        short8 av = *(const short8*)&As[wid * 32 + f * 16 + lr][k0 + lk];
        accd[f] = __builtin_amdgcn_mfma_f32_16x16x32_bf16(av, bw, accd[f], 0, 0, 0);
      }
    }
    if (lr < 8) {
#pragma unroll
      for (int f = 0; f < 2; ++f) {
        int row0 = m0 + wid * 32 + f * 16 + (lane >> 4) * 4;
#pragma unroll
        for (int j = 0; j < 4; ++j)
          dtraw[(size_t)(row0 + j) * 8 + lr] = accd[f][j];
      }
    }
  }
  __syncthreads();   // all LDS reads done; reuse As region as Vt
  {
    unsigned short (*Vt)[136] = (unsigned short(*)[136])&As[0][0];
#pragma unroll
    for (int mi = 0; mi < 4; ++mi) {
#pragma unroll
      for (int ni = 0; ni < 4; ++ni) {
        int row0 = wm * 64 + mi * 16 + (lane >> 4) * 4;
        int col = wn * 64 + ni * 16 + lr;
#pragma unroll
        for (int j = 0; j < 4; ++j)
          Vt[row0 + j][col] = (unsigned short)f2bf(acc[mi][ni][j]);
      }
    }
    __syncthreads();
    const int row = tid >> 4, cs = (tid & 15) * 8;
#pragma unroll
    for (int it = 0; it < 8; ++it) {
      int rr2 = it * 16 + row;
      *(uint4*)(Czx + (size_t)(m0 + rr2) * DIN + n0 + cs) = *(const uint4*)&Vt[rr2][cs];
    }
  }
}

// ---------------- fused gate+RMS + out-proj + bf16 residual + next-LN ----------------
__global__ __launch_bounds__(256) void gemm_out_fused_ln(
    const unsigned short* __restrict__ ysc, const unsigned short* __restrict__ zx,
    const float* __restrict__ nw, const unsigned short* __restrict__ B,
    unsigned short* __restrict__ tres, const float* __restrict__ lnw,
    const float* __restrict__ lnb, unsigned* __restrict__ tnb) {
  __shared__ short As[128][40];
  __shared__ short Bs[128][40];
  __shared__ unsigned short Vt[128][136];
  __shared__ float rs_g[128], mu_s[128], rs_s[128];
  const int tid = threadIdx.x;
  const int lane = tid & 63, wid = tid >> 6;
  const int wm = wid >> 1, wn = wid & 1;
  const int m0 = blockIdx.x * 128;
  const int r = tid >> 1, hf = tid & 1;
  const int lr = lane & 15, lk = (lane >> 4) * 8;
  f32x4 acc[4][4] = {};
  float ssg = 0.f;
  for (int k0 = 0; k0 < 256; k0 += 32) {
    // stage A: gate on the fly
    {
      int col = k0 + hf * 16;
      const unsigned short* yp = ysc + (size_t)(m0 + r) * DI + col;
      const unsigned short* zp = zx + (size_t)(m0 + r) * DIN + col;
      short8 y0 = *(const short8*)(yp);
      short8 y1 = *(const short8*)(yp + 8);
      short8 z0 = *(const short8*)(zp);
      short8 z1 = *(const short8*)(zp + 8);
      float4 nw0 = *(const float4*)(nw + col);
      float4 nw1 = *(const float4*)(nw + col + 4);
      float4 nw2 = *(const float4*)(nw + col + 8);
      float4 nw3 = *(const float4*)(nw + col + 12);
      float nwv[16] = {nw0.x, nw0.y, nw0.z, nw0.w, nw1.x, nw1.y, nw1.z, nw1.w,
                       nw2.x, nw2.y, nw2.z, nw2.w, nw3.x, nw3.y, nw3.z, nw3.w};
      short8 a0, a1;
#pragma unroll
      for (int j = 0; j < 8; ++j) {
        float y = bf2f((unsigned short)y0[j]);
        float z = bf2f((unsigned short)z0[j]);
        float g = y * fast_silu(z);
        ssg += g * g;
        a0[j] = f2bf(g * nwv[j]);
        float y2 = bf2f((unsigned short)y1[j]);
        float z2 = bf2f((unsigned short)z1[j]);
        float g2 = y2 * fast_silu(z2);
        ssg += g2 * g2;
        a1[j] = f2bf(g2 * nwv[8 + j]);
      }
      *(short8*)&As[r][hf * 16] = a0;
      *(short8*)&As[r][hf * 16 + 8] = a1;
    }
    {
      const unsigned short* bp = B + (size_t)r * 256 + k0 + hf * 16;
      *(short8*)&Bs[r][hf * 16] = *(const short8*)(bp);
      *(short8*)&Bs[r][hf * 16 + 8] = *(const short8*)(bp + 8);
    }
    __syncthreads();
    short8 af[4], bfr[4];
#pragma unroll
    for (int mi = 0; mi < 4; ++mi) af[mi] = *(const short8*)&As[wm * 64 + mi * 16 + lr][lk];
#pragma unroll
    for (int ni = 0; ni < 4; ++ni) bfr[ni] = *(const short8*)&Bs[wn * 64 + ni * 16 + lr][lk];
#pragma unroll
    for (int mi = 0; mi < 4; ++mi)
#pragma unroll
      for (int ni = 0; ni < 4; ++ni)
        acc[mi][ni] = __builtin_amdgcn_mfma_f32_16x16x32_bf16(af[mi], bfr[ni], acc[mi][ni], 0, 0, 0);
    __syncthreads();
  }
  // complete row rms: two threads per row
  ssg += __shfl_xor(ssg, 1);
  if (hf == 0) rs_g[r] = rsqrtf(ssg * (1.f / 256.f) + EPSF);
  __syncthreads();
  // epilogue: rms scale + bf16 residual add/store, bf16 LDS tile
#pragma unroll
  for (int mi = 0; mi < 4; ++mi) {
#pragma unroll
    for (int ni = 0; ni < 4; ++ni) {
      int row0 = wm * 64 + mi * 16 + (lane >> 4) * 4;
      int col = wn * 64 + ni * 16 + lr;
#pragma unroll
      for (int j = 0; j < 4; ++j) {
        int row = row0 + j;
        size_t idx = (size_t)(m0 + row) * 128 + col;
        float v = acc[mi][ni][j] * rs_g[row] + bf2f(tres[idx]);
        unsigned short us = (unsigned short)f2bf(v);
        tres[idx] = us;
        Vt[row][col] = us;
      }
    }
  }
  __syncthreads();
  // per-row LN stats (2 threads per row)
  {
    float s = 0.f, ss = 0.f;
#pragma unroll
    for (int kk = 0; kk < 8; ++kk) {
      short8 vv = *(const short8*)&Vt[r][hf * 64 + kk * 8];
#pragma unroll
      for (int j = 0; j < 8; ++j) {
        float f = bf2f((unsigned short)vv[j]);
        s += f; ss += f * f;
      }
    }
    s += __shfl_xor(s, 1);
    ss += __shfl_xor(ss, 1);
    if (hf == 0) {
      float mu = s * (1.f / 128.f);
      mu_s[r] = mu;
      rs_s[r] = rsqrtf(ss * (1.f / 128.f) - mu * mu + EPSF);
    }
  }
  __syncthreads();
  // LN write: packed bf16, coalesced
  float w0 = lnw[lane * 2], w1 = lnw[lane * 2 + 1];
  float b0 = lnb[lane * 2], b1 = lnb[lane * 2 + 1];
  for (int it = 0; it < 32; ++it) {
    int row = it * 4 + wid;
    float mu = mu_s[row], rr = rs_s[row];
    float v0 = bf2f(Vt[row][lane * 2]);
    float v1 = bf2f(Vt[row][lane * 2 + 1]);
    unsigned lo = (unsigned short)f2bf((v0 - mu) * rr * w0 + b0);
    unsigned hi = (unsigned short)f2bf((v1 - mu) * rr * w1 + b1);
    tnb[(size_t)(m0 + row) * 64 + lane] = lo | (hi << 16);
  }
}

// ---------------- patch-embed bf16 MFMA GEMM (bf16 out) ----------------
__global__ __launch_bounds__(256) void gemm_bf16_patch(
    const float* __restrict__ X, const float* __restrict__ B,
    const float* __restrict__ bias, unsigned short* __restrict__ C) {
  __shared__ short As[128][40];
  __shared__ short Bs[128][40];
  const int tid = threadIdx.x;
  const int lane = tid & 63, wid = tid >> 6;
  const int wm = wid >> 1, wn = wid & 1;
  const int m0 = blockIdx.x * 128;
  const int r = tid >> 1, hf = tid & 1;
  const int lr = lane & 15, lk = (lane >> 4) * 8;
  const int m = m0 + r;
  const int bb = m >> 8, px = (m >> 4) & 15, py = m & 15;
  f32x4 acc[4][4] = {};
  for (int k0 = 0; k0 < 768; k0 += 32) {
    int k = k0 + hf * 16;
    int c = k >> 8, dx = (k >> 4) & 15;
    {
      const float* ap = X + (((size_t)(bb * 3 + c) * 256 + px * 16 + dx) * 256 + py * 16);
      float4 v0 = *(const float4*)(ap + 0);
      float4 v1 = *(const float4*)(ap + 4);
      float4 v2 = *(const float4*)(ap + 8);
      float4 v3 = *(const float4*)(ap + 12);
      short8 s0, s1;
      s0[0] = f2bf(v0.x); s0[1] = f2bf(v0.y); s0[2] = f2bf(v0.z); s0[3] = f2bf(v0.w);
      s0[4] = f2bf(v1.x); s0[5] = f2bf(v1.y); s0[6] = f2bf(v1.z); s0[7] = f2bf(v1.w);
      s1[0] = f2bf(v2.x); s1[1] = f2bf(v2.y); s1[2] = f2bf(v2.z); s1[3] = f2bf(v2.w);
      s1[4] = f2bf(v3.x); s1[5] = f2bf(v3.y); s1[6] = f2bf(v3.z); s1[7] = f2bf(v3.w);
      *(short8*)&As[r][hf * 16] = s0;
      *(short8*)&As[r][hf * 16 + 8] = s1;
    }
    {
      const float* bp = B + (size_t)r * 768 + k;
      float4 v0 = *(const float4*)(bp + 0);
      float4 v1 = *(const float4*)(bp + 4);
      float4 v2 = *(const float4*)(bp + 8);
      float4 v3 = *(const float4*)(bp + 12);
      short8 s0, s1;
      s0[0] = f2bf(v0.x); s0[1] = f2bf(v0.y); s0[2] = f2bf(v0.z); s0[3] = f2bf(v0.w);
      s0[4] = f2bf(v1.x); s0[5] = f2bf(v1.y); s0[6] = f2bf(v1.z); s0[7] = f2bf(v1.w);
      s1[0] = f2bf(v2.x); s1[1] = f2bf(v2.y); s1[2] = f2bf(v2.z); s1[3] = f2bf(v2.w);
      s1[4] = f2bf(v3.x); s1[5] = f2bf(v3.y); s1[6] = f2bf(v3.z); s1[7] = f2bf(v3.w);
      *(short8*)&Bs[r][hf * 16] = s0;
      *(short8*)&Bs[r][hf * 16 + 8] = s1;
    }
    __syncthreads();
    short8 af[4], bfr[4];
#pragma unroll
    for (int mi = 0; mi < 4; ++mi) af[mi] = *(const short8*)&As[wm * 64 + mi * 16 + lr][lk];
#pragma unroll
    for (int ni = 0; ni < 4; ++ni) bfr[ni] = *(const short8*)&Bs[wn * 64 + ni * 16 + lr][lk];
#pragma unroll
    for (int mi = 0; mi < 4; ++mi)
#pragma unroll
      for (int ni = 0; ni < 4; ++ni)
        acc[mi][ni] = __builtin_amdgcn_mfma_f32_16x16x32_bf16(af[mi], bfr[ni], acc[mi][ni], 0, 0, 0);
    __syncthreads();
  }
#pragma unroll
  for (int mi = 0; mi < 4; ++mi) {
#pragma unroll
    for (int ni = 0; ni < 4; ++ni) {
      int row0 = m0 + wm * 64 + mi * 16 + (lane >> 4) * 4;
      int col = wn * 64 + ni * 16 + (lane & 15);
#pragma unroll
      for (int j = 0; j < 4; ++j)
        C[(size_t)(row0 + j) * 128 + col] = (unsigned short)f2bf(acc[mi][ni][j] + bias[col]);
    }
  }
}

// ---------------- fused pe-LN (bf16, in place) + block-0 LN (bf16 out) ----------------
__global__ __launch_bounds__(256) void ln_pe0_kernel(
    unsigned* t, unsigned* out,
    const float* __restrict__ pe_w, const float* __restrict__ pe_b,
    const float* __restrict__ l0w, const float* __restrict__ l0b) {
  int wid = threadIdx.x >> 6, lane = threadIdx.x & 63;
  size_t token = (size_t)blockIdx.x * 4 + wid;
  unsigned* p = t + token * 64;
  unsigned u = p[lane];
  float vx = bf2f((unsigned short)(u & 0xffff));
  float vy = bf2f((unsigned short)(u >> 16));
  // pe-LN
  float s = vx + vy;
#pragma unroll
  for (int off = 1; off < 64; off <<= 1) s += __shfl_xor(s, off);
  float mu = s * (1.f / 128.f);
  float dx = vx - mu, dy = vy - mu;
  float vs = dx * dx + dy * dy;
#pragma unroll
  for (int off = 1; off < 64; off <<= 1) vs += __shfl_xor(vs, off);
  float r = rsqrtf(vs * (1.f / 128.f) + EPSF);
  float t0 = dx * r * pe_w[lane * 2 + 0] + pe_b[lane * 2 + 0];
  float t1 = dy * r * pe_w[lane * 2 + 1] + pe_b[lane * 2 + 1];
  unsigned short s0 = (unsigned short)f2bf(t0);
  unsigned short s1 = (unsigned short)f2bf(t1);
  p[lane] = (unsigned)s0 | ((unsigned)s1 << 16);
  // block-0 LN on the STORED (rounded) residual values for consistency
  float r0 = bf2f(s0), r1 = bf2f(s1);
  float s2 = r0 + r1;
#pragma unroll
  for (int off = 1; off < 64; off <<= 1) s2 += __shfl_xor(s2, off);
  float mu2 = s2 * (1.f / 128.f);
  float d0 = r0 - mu2, d1 = r1 - mu2;
  float vs2 = d0 * d0 + d1 * d1;
#pragma unroll
  for (int off = 1; off < 64; off <<= 1) vs2 += __shfl_xor(vs2, off);
  float r2 = rsqrtf(vs2 * (1.f / 128.f) + EPSF);
  unsigned lo = (unsigned short)f2bf(d0 * r2 * l0w[lane * 2 + 0] + l0b[lane * 2 + 0]);
  unsigned hi = (unsigned short)f2bf(d1 * r2 * l0w[lane * 2 + 1] + l0b[lane * 2 + 1]);
  out[token * 64 + lane] = lo | (hi << 16);
}

// ---------------- chunked SSM scan, 4 heads/block; conv+dt fused; S shared 4-way ----------------
// grid = 512; b = bid&255, hq = bid>>8 (heads 4hq..4hq+3). 256 threads (4 waves).
// B/C conv+staging and S = C@B^T computed ONCE per block (shared by 4 heads).
// P computed in two sequential phases reusing Cb/Bb: phase A = heads 0,1; phase B = 2,3.
// Wave w owns head w's full h-update (32 rows).
__global__ __launch_bounds__(256, 2) void scan_chunk_kernel(
    const unsigned short* __restrict__ zx,   // [T][648] bf16 (cols 256.. = pre-conv xbc)
    const float* __restrict__ dtraw,         // [T][8] fp32
    const float* __restrict__ dtb,           // [8]
    const float* __restrict__ A_log,         // [8]
    const float* __restrict__ cw,            // [384][4] conv weights
    const float* __restrict__ cbv_g,         // [384] conv bias
    const float* __restrict__ Dp,            // [8]
    unsigned short* __restrict__ ysc) {      // [T][256] bf16
  const int b = blockIdx.x & 255, hq = blockIdx.x >> 8;
  const int h0 = hq * 4;
  const int tid = threadIdx.x;
  const int w = tid >> 6, lane = tid & 63;
  const int lr = lane & 15, lj = lane >> 4;
  __shared__ __align__(16) unsigned short Cb[64][72];    // C rows; P0 / P2 after bar2
  __shared__ __align__(16) unsigned short Bb[64][72];    // B rows; P1 / P3 after bar2
  __shared__ __align__(16) unsigned short BbT[64][72];   // [n][s]
  __shared__ __align__(16) unsigned short xT[4][32][72]; // per-head x [p][t]
  __shared__ __align__(16) unsigned short hbT[4][32][72];// per-head h [p][n]
  __shared__ float la[4][64], dtc[4][64], wt[4][64];
  for (int i = tid; i < 4608; i += 256) ((unsigned*)hbT)[i] = 0;
  f32x4 acc_h[8] = {};    // wave w: head w, rows rh*16.. (rh = frag>>2), cols ni*16..
  const float dp0 = Dp[h0], dp1 = Dp[h0 + 1], dp2 = Dp[h0 + 2], dp3 = Dp[h0 + 3];
  __syncthreads();

  for (int c = 0; c < 4; ++c) {
    const int tok0 = b * 256 + c * 64;
    // ---- dt + prefix-scan: wave w -> head h0+w ----
    {
      int hh = h0 + w;
      float raw = dtraw[(size_t)(tok0 + lane) * 8 + hh] + dtb[hh];
      float dt = raw > 20.f ? raw : log1pf(expf(raw));
      float v = -expf(A_log[hh]) * dt;
#pragma unroll
      for (int off = 1; off < 64; off <<= 1) {
        float u = __shfl_up(v, off);
        if (lane >= off) v += u;
      }
      la[w][lane] = v;
      dtc[w][lane] = dt;
    }
    // ---- staging with fused conv1d + SiLU: 256 x-items (4 heads) + 128 B + 128 C ----
    for (int it = tid; it < 512; it += 256) {
      int t0, ch, kind, sub;
      if (it < 256) {
        int hx = it >> 6, id = it & 63;
        t0 = (id >> 2) * 4; sub = (id & 3) * 8;
        ch = (h0 + hx) * 32 + sub; kind = hx;
      } else if (it < 384) {
        int id = it - 256;
        t0 = (id >> 3) * 4; sub = (id & 7) * 8;
        ch = 256 + sub; kind = 4;
      } else {
        int id = it - 384;
        t0 = (id >> 3) * 4; sub = (id & 7) * 8;
        ch = 320 + sub; kind = 5;
      }
      const unsigned short* zp = zx + (size_t)(tok0 + t0) * DIN + 256 + ch;
      const int t0loc = c * 64 + t0;
      short8 rr[7];
      if (t0loc >= 3) {
#pragma unroll
        for (int d = 0; d < 7; ++d)
          rr[d] = *(const short8*)(zp + (ptrdiff_t)(d - 3) * DIN);
      } else {
#pragma unroll
        for (int d = 0; d < 7; ++d) {
          short8 z8 = {};
          if (t0loc + d - 3 >= 0) z8 = *(const short8*)(zp + (ptrdiff_t)(d - 3) * DIN);
          rr[d] = z8;
        }
      }
      float4 cwv[8];
      float cbl[8];
#pragma unroll
      for (int j = 0; j < 8; ++j) {
        cwv[j] = *(const float4*)(cw + (ch + j) * 4);
        cbl[j] = cbv_g[ch + j];
      }
      short8 o[4];
#pragma unroll
      for (int tt = 0; tt < 4; ++tt) {
#pragma unroll
        for (int j = 0; j < 8; ++j) {
          float a = cbl[j]
                  + cwv[j].x * bf2f((unsigned short)rr[tt + 0][j])
                  + cwv[j].y * bf2f((unsigned short)rr[tt + 1][j])
                  + cwv[j].z * bf2f((unsigned short)rr[tt + 2][j])
                  + cwv[j].w * bf2f((unsigned short)rr[tt + 3][j]);
          o[tt][j] = f2bf(fast_silu(a));
        }
      }
      if (kind < 4) {
#pragma unroll
        for (int j = 0; j < 8; ++j) {
          ushort4 v;
          v.x = (unsigned short)o[0][j]; v.y = (unsigned short)o[1][j];
          v.z = (unsigned short)o[2][j]; v.w = (unsigned short)o[3][j];
          *(ushort4*)&xT[kind][sub + j][t0] = v;
        }
      } else if (kind == 4) {
        *(short8*)&Bb[t0 + 0][sub] = o[0];
        *(short8*)&Bb[t0 + 1][sub] = o[1];
        *(short8*)&Bb[t0 + 2][sub] = o[2];
        *(short8*)&Bb[t0 + 3][sub] = o[3];
#pragma unroll
        for (int j = 0; j < 8; ++j) {
          ushort4 v;
          v.x = (unsigned short)o[0][j]; v.y = (unsigned short)o[1][j];
          v.z = (unsigned short)o[2][j]; v.w = (unsigned short)o[3][j];
          *(ushort4*)&BbT[sub + j][t0] = v;
        }
      } else {
        *(short8*)&Cb[t0 + 0][sub] = o[0];
        *(short8*)&Cb[t0 + 1][sub] = o[1];
        *(short8*)&Cb[t0 + 2][sub] = o[2];
        *(short8*)&Cb[t0 + 3][sub] = o[3];
      }
    }
    __syncthreads();   // bar1
    wt[w][lane] = __expf(la[w][63] - la[w][lane]) * dtc[w][lane];   // own-wave use only
    // ---- phase1: S = C@B^T (shared), y_inter for 4 heads ----
    short8 afC0 = *(const short8*)&Cb[w * 16 + lr][lj * 8];
    short8 afC1 = *(const short8*)&Cb[w * 16 + lr][32 + lj * 8];
    f32x4 acc_s[4] = {};
#pragma unroll
    for (int ni = 0; ni < 4; ++ni) {
      short8 bf0 = *(const short8*)&Bb[ni * 16 + lr][lj * 8];
      short8 bf1 = *(const short8*)&Bb[ni * 16 + lr][32 + lj * 8];
      acc_s[ni] = __builtin_amdgcn_mfma_f32_16x16x32_bf16(afC0, bf0, acc_s[ni], 0, 0, 0);
      acc_s[ni] = __builtin_amdgcn_mfma_f32_16x16x32_bf16(afC1, bf1, acc_s[ni], 0, 0, 0);
    }
    f32x4 acc_y[4][2] = {};
#pragma unroll
    for (int hh = 0; hh < 4; ++hh) {
#pragma unroll
      for (int ni = 0; ni < 2; ++ni) {
        short8 hf0 = *(const short8*)&hbT[hh][ni * 16 + lr][lj * 8];
        short8 hf1 = *(const short8*)&hbT[hh][ni * 16 + lr][32 + lj * 8];
        acc_y[hh][ni] = __builtin_amdgcn_mfma_f32_16x16x32_bf16(afC0, hf0, acc_y[hh][ni], 0, 0, 0);
        acc_y[hh][ni] = __builtin_amdgcn_mfma_f32_16x16x32_bf16(afC1, hf1, acc_y[hh][ni], 0, 0, 0);
      }
    }
#pragma unroll
    for (int j = 0; j < 4; ++j) {
      int t = w * 16 + lj * 4 + j;
#pragma unroll
      for (int hh = 0; hh < 4; ++hh) {
        float at = __expf(la[hh][t]);
        acc_y[hh][0][j] *= at;
        acc_y[hh][1][j] *= at;
      }
    }
    // ---- h-update: wave w -> head w, full 32 rows (reads BbT, xT[w], wt[w]) ----
    {
      float aend = __expf(la[w][63]);
#pragma unroll
      for (int f = 0; f < 8; ++f)
#pragma unroll
        for (int j = 0; j < 4; ++j) acc_h[f][j] *= aend;
#pragma unroll
      for (int kk = 0; kk < 2; ++kk) {
#pragma unroll
        for (int rh = 0; rh < 2; ++rh) {
          short8 xv = *(const short8*)&xT[w][rh * 16 + lr][kk * 32 + lj * 8];
          short8 axf;
#pragma unroll
          for (int j = 0; j < 8; ++j)
            axf[j] = f2bf(bf2f((unsigned short)xv[j]) * wt[w][kk * 32 + lj * 8 + j]);
#pragma unroll
          for (int ni = 0; ni < 4; ++ni) {
            short8 bw = *(const short8*)&BbT[ni * 16 + lr][kk * 32 + lj * 8];
            acc_h[rh * 4 + ni] = __builtin_amdgcn_mfma_f32_16x16x32_bf16(axf, bw, acc_h[rh * 4 + ni], 0, 0, 0);
          }
        }
      }
    }
    __syncthreads();   // bar2: Cb/Bb row reads done
    // ---- P phase A: P0 -> Cb, P1 -> Bb ----
#pragma unroll
    for (int ni = 0; ni < 4; ++ni) {
      int s = ni * 16 + lr;
      float las0 = la[0][s], dts0 = dtc[0][s];
      float las1 = la[1][s], dts1 = dtc[1][s];
#pragma unroll
      for (int j = 0; j < 4; ++j) {
        int t = w * 16 + lj * 4 + j;
        float pv0 = 0.f, pv1 = 0.f;
        if (s <= t) {
          pv0 = acc_s[ni][j] * __expf(la[0][t] - las0) * dts0;
          pv1 = acc_s[ni][j] * __expf(la[1][t] - las1) * dts1;
        }
        Cb[t][s] = (unsigned short)f2bf(pv0);
        Bb[t][s] = (unsigned short)f2bf(pv1);
      }
    }
    __syncthreads();   // bar3
    // ---- PV A + y epilogue heads 0,1 ----
    {
      short8 aP0a = *(const short8*)&Cb[w * 16 + lr][lj * 8];
      short8 aP0b = *(const short8*)&Cb[w * 16 + lr][32 + lj * 8];
      short8 aP1a = *(const short8*)&Bb[w * 16 + lr][lj * 8];
      short8 aP1b = *(const short8*)&Bb[w * 16 + lr][32 + lj * 8];
#pragma unroll
      for (int ni = 0; ni < 2; ++ni) {
        short8 x0a = *(const short8*)&xT[0][ni * 16 + lr][lj * 8];
        short8 x0b = *(const short8*)&xT[0][ni * 16 + lr][32 + lj * 8];
        acc_y[0][ni] = __builtin_amdgcn_mfma_f32_16x16x32_bf16(aP0a, x0a, acc_y[0][ni], 0, 0, 0);
        acc_y[0][ni] = __builtin_amdgcn_mfma_f32_16x16x32_bf16(aP0b, x0b, acc_y[0][ni], 0, 0, 0);
        short8 x1a = *(const short8*)&xT[1][ni * 16 + lr][lj * 8];
        short8 x1b = *(const short8*)&xT[1][ni * 16 + lr][32 + lj * 8];
        acc_y[1][ni] = __builtin_amdgcn_mfma_f32_16x16x32_bf16(aP1a, x1a, acc_y[1][ni], 0, 0, 0);
        acc_y[1][ni] = __builtin_amdgcn_mfma_f32_16x16x32_bf16(aP1b, x1b, acc_y[1][ni], 0, 0, 0);
      }
#pragma unroll
      for (int ni = 0; ni < 2; ++ni) {
#pragma unroll
        for (int j = 0; j < 4; ++j) {
          int t = w * 16 + lj * 4 + j;
          int p = ni * 16 + lr;
          size_t base = (size_t)(tok0 + t) * DI;
          float yv0 = acc_y[0][ni][j] + dp0 * bf2f(xT[0][p][t]);
          ysc[base + (h0 + 0) * 32 + p] = (unsigned short)f2bf(yv0);
          float yv1 = acc_y[1][ni][j] + dp1 * bf2f(xT[1][p][t]);
          ysc[base + (h0 + 1) * 32 + p] = (unsigned short)f2bf(yv1);
        }
      }
    }
    __syncthreads();   // bar3b: P0/P1 reads done
    // ---- P phase B: P2 -> Cb, P3 -> Bb ----
#pragma unroll
    for (int ni = 0; ni < 4; ++ni) {
      int s = ni * 16 + lr;
      float las2 = la[2][s], dts2 = dtc[2][s];
      float las3 = la[3][s], dts3 = dtc[3][s];
#pragma unroll
      for (int j = 0; j < 4; ++j) {
        int t = w * 16 + lj * 4 + j;
        float pv2 = 0.f, pv3 = 0.f;
        if (s <= t) {
          pv2 = acc_s[ni][j] * __expf(la[2][t] - las2) * dts2;
          pv3 = acc_s[ni][j] * __expf(la[3][t] - las3) * dts3;
        }
        Cb[t][s] = (unsigned short)f2bf(pv2);
        Bb[t][s] = (unsigned short)f2bf(pv3);
      }
    }
    __syncthreads();   // bar3c
    // ---- PV B + y epilogue heads 2,3 ----
    {
      short8 aP2a = *(const short8*)&Cb[w * 16 + lr][lj * 8];
      short8 aP2b = *(const short8*)&Cb[w * 16 + lr][32 + lj * 8];
      short8 aP3a = *(const short8*)&Bb[w * 16 + lr][lj * 8];
      short8 aP3b = *(const short8*)&Bb[w * 16 + lr][32 + lj * 8];
#pragma unroll
      for (int ni = 0; ni < 2; ++ni) {
        short8 x2a = *(const short8*)&xT[2][ni * 16 + lr][lj * 8];
        short8 x2b = *(const short8*)&xT[2][ni * 16 + lr][32 + lj * 8];
        acc_y[2][ni] = __builtin_amdgcn_mfma_f32_16x16x32_bf16(aP2a, x2a, acc_y[2][ni], 0, 0, 0);
        acc_y[2][ni] = __builtin_amdgcn_mfma_f32_16x16x32_bf16(aP2b, x2b, acc_y[2][ni], 0, 0, 0);
        short8 x3a = *(const short8*)&xT[3][ni * 16 + lr][lj * 8];
        short8 x3b = *(const short8*)&xT[3][ni * 16 + lr][32 + lj * 8];
        acc_y[3][ni] = __builtin_amdgcn_mfma_f32_16x16x32_bf16(aP3a, x3a, acc_y[3][ni], 0, 0, 0);
        acc_y[3][ni] = __builtin_amdgcn_mfma_f32_16x16x32_bf16(aP3b, x3b, acc_y[3][ni], 0, 0, 0);
      }
#pragma unroll
      for (int ni = 0; ni < 2; ++ni) {
#pragma unroll
        for (int j = 0; j < 4; ++j) {
          int t = w * 16 + lj * 4 + j;
          int p = ni * 16 + lr;
          size_t base = (size_t)(tok0 + t) * DI;
          float yv2 = acc_y[2][ni][j] + dp2 * bf2f(xT[2][p][t]);
          ysc[base + (h0 + 2) * 32 + p] = (unsigned short)f2bf(yv2);
          float yv3 = acc_y[3][ni][j] + dp3 * bf2f(xT[3][p][t]);
          ysc[base + (h0 + 3) * 32 + p] = (unsigned short)f2bf(yv3);
        }
      }
    }
    // ---- h writeback: wave w -> hbT[w], 32 rows ----
#pragma unroll
    for (int rh = 0; rh < 2; ++rh)
#pragma unroll
      for (int ni = 0; ni < 4; ++ni)
#pragma unroll
        for (int j = 0; j < 4; ++j)
          hbT[w][rh * 16 + lj * 4 + j][ni * 16 + lr] = (unsigned short)f2bf(acc_h[rh * 4 + ni][j]);
    __syncthreads();   // bar4
  }
}

// ---------------- head: column mean + matmul + L2 normalize (fused) ----------------
__global__ __launch_bounds__(128) void head_kernel(
    const unsigned short* __restrict__ tn, const float* __restrict__ hw,
    const float* __restrict__ hb, float* __restrict__ out) {
  __shared__ float tm[128];
  __shared__ float red[2];
  int b = blockIdx.x, o = threadIdx.x;
  {
    const unsigned short* p = tn + (size_t)b * 256 * 128 + o;
    float acc = 0.f;
    for (int l = 0; l < 256; ++l) acc += bf2f(p[l * 128]);
    tm[o] = acc * (1.f / 256.f);
  }
  __syncthreads();
  float acc = hb[o];
  for (int e = 0; e < 128; ++e) acc += tm[e] * hw[o * 128 + e];
  float ss = acc * acc;
#pragma unroll
  for (int off = 1; off < 64; off <<= 1) ss += __shfl_xor(ss, off);
  if ((o & 63) == 0) red[o >> 6] = ss;
  __syncthreads();
  float nrm = fmaxf(sqrtf(red[0] + red[1]), 1e-12f);
  out[b * 128 + o] = acc / nrm;
}

extern "C" void kernel_launch(void* const* d_in, const int* in_sizes, int n_in,
                              void* d_out, int out_size, void* d_ws, size_t ws_size,
                              hipStream_t stream) {
  const float* x      = (const float*)d_in[0];
  const float* conv_w = (const float*)d_in[1];
  const float* conv_b = (const float*)d_in[2];
  const float* pe_w   = (const float*)d_in[3];
  const float* pe_b   = (const float*)d_in[4];
  const float* ln_w   = (const float*)d_in[5];
  const float* ln_b   = (const float*)d_in[6];
  const float* in_w   = (const float*)d_in[7];
  const float* c1w    = (const float*)d_in[8];
  const float* c1b    = (const float*)d_in[9];
  const float* dtb    = (const float*)d_in[10];
  const float* A_log  = (const float*)d_in[11];
  const float* Dp     = (const float*)d_in[12];
  const float* nw     = (const float*)d_in[13];
  const float* ow     = (const float*)d_in[14];
  const float* fn_w   = (const float*)d_in[15];
  const float* fn_b   = (const float*)d_in[16];
  const float* hw     = (const float*)d_in[17];
  const float* hb     = (const float*)d_in[18];
  float* out = (float*)d_out;

  const size_t T = TTOK;
  char* w8 = (char*)d_ws;
  unsigned short* t_buf = (unsigned short*)w8;   w8 += T * 128 * 2;   // residual bf16
  unsigned*       tnb   = (unsigned*)w8;         w8 += T * 128 * 2;   // ln out bf16
  unsigned short* zx    = (unsigned short*)w8;   w8 += T * (size_t)DIN * 2; // in-proj bf16
  float*          dtraw = (float*)w8;            w8 += T * 8 * 4;
  unsigned short* ysc   = (unsigned short*)w8;   w8 += T * (size_t)DI * 2;  // scan out bf16
  unsigned short* in_wb = (unsigned short*)w8;   w8 += (size_t)NL * DIN * EE * 2;
  unsigned short* owb   = (unsigned short*)w8;   w8 += (size_t)NL * EE * DI * 2;
  if ((size_t)(w8 - (char*)d_ws) > ws_size) return;  // workspace too small

  // one-shot weight conversion (NL*DIN*EE = 331776 = 1296*256)
  cvt_w_kernel<<<1296, 256, 0, stream>>>(in_w, ow, in_wb, owb);

  // patch embed + bias (bf16 residual), then fused pe-LN + block-0 LN
  gemm_bf16_patch<<<dim3(512, 1), 256, 0, stream>>>(x, conv_w, conv_b, t_buf);
  ln_pe0_kernel<<<16384, 256, 0, stream>>>((unsigned*)t_buf, tnb, pe_w, pe_b, ln_w, ln_b);

  for (int i = 0; i < NL; ++i) {
    gemm_in_proj<<<dim3(5, 512), 256, 0, stream>>>(
        (const unsigned short*)tnb, in_wb + (size_t)i * DIN * EE,
        in_wb + (size_t)i * DIN * EE + 640 * 128, zx, dtraw);
    scan_chunk_kernel<<<512, 256, 0, stream>>>(
        zx, dtraw, dtb + i * HH, A_log + i * HH,
        c1w + (size_t)i * XBC * DC, c1b + (size_t)i * XBC, Dp + i * HH, ysc);
    const float* nlw = (i < NL - 1) ? (ln_w + (i + 1) * 128) : fn_w;
    const float* nlb = (i < NL - 1) ? (ln_b + (i + 1) * 128) : fn_b;
    gemm_out_fused_ln<<<512, 256, 0, stream>>>(
        ysc, zx, nw + i * DI, owb + (size_t)i * EE * DI, t_buf, nlw, nlb, tnb);
  }

  // tnb holds final-LN output (fused in last gemm_out_fused_ln)
  head_kernel<<<256, 128, 0, stream>>>((const unsigned short*)tnb, hw, hb, out);
}

// Round 29
// 546.015 us; speedup vs baseline: 1.0741x; 1.0179x over previous
//
#include <hip/hip_runtime.h>
#include <math.h>

// ---------------- constants ----------------
#define EE 128
#define DI 256
#define HH 8
#define PP 32
#define NN 64
#define DC 4
#define XBC 384
#define DIN 648
#define NL 4
#define LSEQ 256
#define BB 256
#define TTOK (BB * LSEQ)   // 65536 tokens
#define EPSF 1e-5f

typedef __attribute__((ext_vector_type(8))) short short8;
typedef __attribute__((ext_vector_type(4))) float f32x4;

__device__ inline short f2bf(float f) {
  unsigned u = __builtin_bit_cast(unsigned, f);
  u += 0x7fff + ((u >> 16) & 1);   // RNE
  return (short)(u >> 16);
}
__device__ inline float bf2f(unsigned short u) {
  unsigned x = ((unsigned)u) << 16;
  return __builtin_bit_cast(float, x);
}
// silu via v_rcp_f32 (<=1 ulp; exact div is a ~15-inst sequence on gfx950)
__device__ inline float fast_silu(float a) {
  return a * __builtin_amdgcn_rcpf(1.f + __expf(-a));
}

// ---------------- one-shot weight conversion fp32 -> bf16 ----------------
__global__ __launch_bounds__(256) void cvt_w_kernel(
    const float* __restrict__ in_w, const float* __restrict__ ow,
    unsigned short* __restrict__ in_wb, unsigned short* __restrict__ owb) {
  int i = blockIdx.x * 256 + threadIdx.x;   // grid covers NL*DIN*EE = 331776
  in_wb[i] = (unsigned short)f2bf(in_w[i]);
  if (i < NL * EE * DI) owb[i] = (unsigned short)f2bf(ow[i]);
}

// ---------------- in-proj GEMM (K=128, N=640 full tiles): single-shot staging ----------------
// grid = dim3(5, 512). n0==0 blocks also compute dtraw = As @ Wdt^T (MFMA, 8 extra/wave)
// reusing the staged A tile — same summation chain as the old n0==640 side-channel.
__global__ __launch_bounds__(256) void gemm_in_proj(
    const unsigned short* __restrict__ A, const unsigned short* __restrict__ B,
    const unsigned short* __restrict__ Wdt,   // [8][128] bf16 (in_wb rows 640..647)
    unsigned short* __restrict__ Czx, float* __restrict__ dtraw) {
  __shared__ __align__(16) unsigned short As[128][136];   // full A tile (K=128)
  __shared__ __align__(16) unsigned short Bs[128][136];   // full B tile
  const int tid = threadIdx.x;
  const int lane = tid & 63, wid = tid >> 6;
  const int wm = wid >> 1, wn = wid & 1;
  const int m0 = blockIdx.y * 128, n0 = blockIdx.x * 128;
  const int r = tid >> 1, hf = tid & 1;
  const int lr = lane & 15, lk = (lane >> 4) * 8;
  // ---- single-shot staging: whole 128x128 A and B tiles ----
  {
    const unsigned short* ap = A + (size_t)(m0 + r) * 128 + hf * 64;
#pragma unroll
    for (int v = 0; v < 8; ++v)
      *(short8*)&As[r][hf * 64 + v * 8] = *(const short8*)(ap + v * 8);
    const unsigned short* bp = B + (size_t)(n0 + r) * 128 + hf * 64;
#pragma unroll
    for (int v = 0; v < 8; ++v)
      *(short8*)&Bs[r][hf * 64 + v * 8] = *(const short8*)(bp + v * 8);
  }
  __syncthreads();
  // ---- all 4 K-steps, no barriers ----
  f32x4 acc[4][4] = {};
#pragma unroll
  for (int ks = 0; ks < 4; ++ks) {
    int k0 = ks * 32;
    short8 af[4], bfr[4];
#pragma unroll
    for (int mi = 0; mi < 4; ++mi) af[mi] = *(const short8*)&As[wm * 64 + mi * 16 + lr][k0 + lk];
#pragma unroll
    for (int ni = 0; ni < 4; ++ni) bfr[ni] = *(const short8*)&Bs[wn * 64 + ni * 16 + lr][k0 + lk];
#pragma unroll
    for (int mi = 0; mi < 4; ++mi)
#pragma unroll
      for (int ni = 0; ni < 4; ++ni)
        acc[mi][ni] = __builtin_amdgcn_mfma_f32_16x16x32_bf16(af[mi], bfr[ni], acc[mi][ni], 0, 0, 0);
  }
  // ---- dt MFMA epilogue (n0==0 blocks): wave wid covers rows wid*32..wid*32+31 ----
  if (n0 == 0) {
    f32x4 accd[2] = {};
#pragma unroll
    for (int ks = 0; ks < 4; ++ks) {
      int k0 = ks * 32;
      short8 bw = {};
      if (lr < 8) bw = *(const short8*)(Wdt + (size_t)lr * 128 + k0 + lk);
#pragma unroll
      for (int f = 0; f < 2; ++f) {
        short8 av = *(const short8*)&As[wid * 32 + f * 16 + lr][k0 + lk];
        accd[f] = __builtin_amdgcn_mfma_f32_16x16x32_bf16(av, bw, accd[f], 0, 0, 0);
      }
    }
    if (lr < 8) {
#pragma unroll
      for (int f = 0; f < 2; ++f) {
        int row0 = m0 + wid * 32 + f * 16 + (lane >> 4) * 4;
#pragma unroll
        for (int j = 0; j < 4; ++j)
          dtraw[(size_t)(row0 + j) * 8 + lr] = accd[f][j];
      }
    }
  }
  __syncthreads();   // all LDS reads done; reuse As region as Vt
  {
    unsigned short (*Vt)[136] = (unsigned short(*)[136])&As[0][0];
#pragma unroll
    for (int mi = 0; mi < 4; ++mi) {
#pragma unroll
      for (int ni = 0; ni < 4; ++ni) {
        int row0 = wm * 64 + mi * 16 + (lane >> 4) * 4;
        int col = wn * 64 + ni * 16 + lr;
#pragma unroll
        for (int j = 0; j < 4; ++j)
          Vt[row0 + j][col] = (unsigned short)f2bf(acc[mi][ni][j]);
      }
    }
    __syncthreads();
    const int row = tid >> 4, cs = (tid & 15) * 8;
#pragma unroll
    for (int it = 0; it < 8; ++it) {
      int rr2 = it * 16 + row;
      *(uint4*)(Czx + (size_t)(m0 + rr2) * DIN + n0 + cs) = *(const uint4*)&Vt[rr2][cs];
    }
  }
}

// ---------------- fused gate+RMS + out-proj + bf16 residual + next-LN ----------------
__global__ __launch_bounds__(256) void gemm_out_fused_ln(
    const unsigned short* __restrict__ ysc, const unsigned short* __restrict__ zx,
    const float* __restrict__ nw, const unsigned short* __restrict__ B,
    unsigned short* __restrict__ tres, const float* __restrict__ lnw,
    const float* __restrict__ lnb, unsigned* __restrict__ tnb) {
  __shared__ short As[128][40];
  __shared__ short Bs[128][40];
  __shared__ unsigned short Vt[128][136];
  __shared__ float rs_g[128], mu_s[128], rs_s[128];
  const int tid = threadIdx.x;
  const int lane = tid & 63, wid = tid >> 6;
  const int wm = wid >> 1, wn = wid & 1;
  const int m0 = blockIdx.x * 128;
  const int r = tid >> 1, hf = tid & 1;
  const int lr = lane & 15, lk = (lane >> 4) * 8;
  f32x4 acc[4][4] = {};
  float ssg = 0.f;
  for (int k0 = 0; k0 < 256; k0 += 32) {
    // stage A: gate on the fly
    {
      int col = k0 + hf * 16;
      const unsigned short* yp = ysc + (size_t)(m0 + r) * DI + col;
      const unsigned short* zp = zx + (size_t)(m0 + r) * DIN + col;
      short8 y0 = *(const short8*)(yp);
      short8 y1 = *(const short8*)(yp + 8);
      short8 z0 = *(const short8*)(zp);
      short8 z1 = *(const short8*)(zp + 8);
      float4 nw0 = *(const float4*)(nw + col);
      float4 nw1 = *(const float4*)(nw + col + 4);
      float4 nw2 = *(const float4*)(nw + col + 8);
      float4 nw3 = *(const float4*)(nw + col + 12);
      float nwv[16] = {nw0.x, nw0.y, nw0.z, nw0.w, nw1.x, nw1.y, nw1.z, nw1.w,
                       nw2.x, nw2.y, nw2.z, nw2.w, nw3.x, nw3.y, nw3.z, nw3.w};
      short8 a0, a1;
#pragma unroll
      for (int j = 0; j < 8; ++j) {
        float y = bf2f((unsigned short)y0[j]);
        float z = bf2f((unsigned short)z0[j]);
        float g = y * fast_silu(z);
        ssg += g * g;
        a0[j] = f2bf(g * nwv[j]);
        float y2 = bf2f((unsigned short)y1[j]);
        float z2 = bf2f((unsigned short)z1[j]);
        float g2 = y2 * fast_silu(z2);
        ssg += g2 * g2;
        a1[j] = f2bf(g2 * nwv[8 + j]);
      }
      *(short8*)&As[r][hf * 16] = a0;
      *(short8*)&As[r][hf * 16 + 8] = a1;
    }
    {
      const unsigned short* bp = B + (size_t)r * 256 + k0 + hf * 16;
      *(short8*)&Bs[r][hf * 16] = *(const short8*)(bp);
      *(short8*)&Bs[r][hf * 16 + 8] = *(const short8*)(bp + 8);
    }
    __syncthreads();
    short8 af[4], bfr[4];
#pragma unroll
    for (int mi = 0; mi < 4; ++mi) af[mi] = *(const short8*)&As[wm * 64 + mi * 16 + lr][lk];
#pragma unroll
    for (int ni = 0; ni < 4; ++ni) bfr[ni] = *(const short8*)&Bs[wn * 64 + ni * 16 + lr][lk];
#pragma unroll
    for (int mi = 0; mi < 4; ++mi)
#pragma unroll
      for (int ni = 0; ni < 4; ++ni)
        acc[mi][ni] = __builtin_amdgcn_mfma_f32_16x16x32_bf16(af[mi], bfr[ni], acc[mi][ni], 0, 0, 0);
    __syncthreads();
  }
  // complete row rms: two threads per row
  ssg += __shfl_xor(ssg, 1);
  if (hf == 0) rs_g[r] = rsqrtf(ssg * (1.f / 256.f) + EPSF);
  __syncthreads();
  // epilogue: rms scale + bf16 residual add/store, bf16 LDS tile
#pragma unroll
  for (int mi = 0; mi < 4; ++mi) {
#pragma unroll
    for (int ni = 0; ni < 4; ++ni) {
      int row0 = wm * 64 + mi * 16 + (lane >> 4) * 4;
      int col = wn * 64 + ni * 16 + lr;
#pragma unroll
      for (int j = 0; j < 4; ++j) {
        int row = row0 + j;
        size_t idx = (size_t)(m0 + row) * 128 + col;
        float v = acc[mi][ni][j] * rs_g[row] + bf2f(tres[idx]);
        unsigned short us = (unsigned short)f2bf(v);
        tres[idx] = us;
        Vt[row][col] = us;
      }
    }
  }
  __syncthreads();
  // per-row LN stats (2 threads per row)
  {
    float s = 0.f, ss = 0.f;
#pragma unroll
    for (int kk = 0; kk < 8; ++kk) {
      short8 vv = *(const short8*)&Vt[r][hf * 64 + kk * 8];
#pragma unroll
      for (int j = 0; j < 8; ++j) {
        float f = bf2f((unsigned short)vv[j]);
        s += f; ss += f * f;
      }
    }
    s += __shfl_xor(s, 1);
    ss += __shfl_xor(ss, 1);
    if (hf == 0) {
      float mu = s * (1.f / 128.f);
      mu_s[r] = mu;
      rs_s[r] = rsqrtf(ss * (1.f / 128.f) - mu * mu + EPSF);
    }
  }
  __syncthreads();
  // LN write: packed bf16, coalesced
  float w0 = lnw[lane * 2], w1 = lnw[lane * 2 + 1];
  float b0 = lnb[lane * 2], b1 = lnb[lane * 2 + 1];
  for (int it = 0; it < 32; ++it) {
    int row = it * 4 + wid;
    float mu = mu_s[row], rr = rs_s[row];
    float v0 = bf2f(Vt[row][lane * 2]);
    float v1 = bf2f(Vt[row][lane * 2 + 1]);
    unsigned lo = (unsigned short)f2bf((v0 - mu) * rr * w0 + b0);
    unsigned hi = (unsigned short)f2bf((v1 - mu) * rr * w1 + b1);
    tnb[(size_t)(m0 + row) * 64 + lane] = lo | (hi << 16);
  }
}

// ---------------- patch-embed bf16 MFMA GEMM (bf16 out) ----------------
__global__ __launch_bounds__(256) void gemm_bf16_patch(
    const float* __restrict__ X, const float* __restrict__ B,
    const float* __restrict__ bias, unsigned short* __restrict__ C) {
  __shared__ short As[128][40];
  __shared__ short Bs[128][40];
  const int tid = threadIdx.x;
  const int lane = tid & 63, wid = tid >> 6;
  const int wm = wid >> 1, wn = wid & 1;
  const int m0 = blockIdx.x * 128;
  const int r = tid >> 1, hf = tid & 1;
  const int lr = lane & 15, lk = (lane >> 4) * 8;
  const int m = m0 + r;
  const int bb = m >> 8, px = (m >> 4) & 15, py = m & 15;
  f32x4 acc[4][4] = {};
  for (int k0 = 0; k0 < 768; k0 += 32) {
    int k = k0 + hf * 16;
    int c = k >> 8, dx = (k >> 4) & 15;
    {
      const float* ap = X + (((size_t)(bb * 3 + c) * 256 + px * 16 + dx) * 256 + py * 16);
      float4 v0 = *(const float4*)(ap + 0);
      float4 v1 = *(const float4*)(ap + 4);
      float4 v2 = *(const float4*)(ap + 8);
      float4 v3 = *(const float4*)(ap + 12);
      short8 s0, s1;
      s0[0] = f2bf(v0.x); s0[1] = f2bf(v0.y); s0[2] = f2bf(v0.z); s0[3] = f2bf(v0.w);
      s0[4] = f2bf(v1.x); s0[5] = f2bf(v1.y); s0[6] = f2bf(v1.z); s0[7] = f2bf(v1.w);
      s1[0] = f2bf(v2.x); s1[1] = f2bf(v2.y); s1[2] = f2bf(v2.z); s1[3] = f2bf(v2.w);
      s1[4] = f2bf(v3.x); s1[5] = f2bf(v3.y); s1[6] = f2bf(v3.z); s1[7] = f2bf(v3.w);
      *(short8*)&As[r][hf * 16] = s0;
      *(short8*)&As[r][hf * 16 + 8] = s1;
    }
    {
      const float* bp = B + (size_t)r * 768 + k;
      float4 v0 = *(const float4*)(bp + 0);
      float4 v1 = *(const float4*)(bp + 4);
      float4 v2 = *(const float4*)(bp + 8);
      float4 v3 = *(const float4*)(bp + 12);
      short8 s0, s1;
      s0[0] = f2bf(v0.x); s0[1] = f2bf(v0.y); s0[2] = f2bf(v0.z); s0[3] = f2bf(v0.w);
      s0[4] = f2bf(v1.x); s0[5] = f2bf(v1.y); s0[6] = f2bf(v1.z); s0[7] = f2bf(v1.w);
      s1[0] = f2bf(v2.x); s1[1] = f2bf(v2.y); s1[2] = f2bf(v2.z); s1[3] = f2bf(v2.w);
      s1[4] = f2bf(v3.x); s1[5] = f2bf(v3.y); s1[6] = f2bf(v3.z); s1[7] = f2bf(v3.w);
      *(short8*)&Bs[r][hf * 16] = s0;
      *(short8*)&Bs[r][hf * 16 + 8] = s1;
    }
    __syncthreads();
    short8 af[4], bfr[4];
#pragma unroll
    for (int mi = 0; mi < 4; ++mi) af[mi] = *(const short8*)&As[wm * 64 + mi * 16 + lr][lk];
#pragma unroll
    for (int ni = 0; ni < 4; ++ni) bfr[ni] = *(const short8*)&Bs[wn * 64 + ni * 16 + lr][lk];
#pragma unroll
    for (int mi = 0; mi < 4; ++mi)
#pragma unroll
      for (int ni = 0; ni < 4; ++ni)
        acc[mi][ni] = __builtin_amdgcn_mfma_f32_16x16x32_bf16(af[mi], bfr[ni], acc[mi][ni], 0, 0, 0);
    __syncthreads();
  }
#pragma unroll
  for (int mi = 0; mi < 4; ++mi) {
#pragma unroll
    for (int ni = 0; ni < 4; ++ni) {
      int row0 = m0 + wm * 64 + mi * 16 + (lane >> 4) * 4;
      int col = wn * 64 + ni * 16 + (lane & 15);
#pragma unroll
      for (int j = 0; j < 4; ++j)
        C[(size_t)(row0 + j) * 128 + col] = (unsigned short)f2bf(acc[mi][ni][j] + bias[col]);
    }
  }
}

// ---------------- fused pe-LN (bf16, in place) + block-0 LN (bf16 out) ----------------
__global__ __launch_bounds__(256) void ln_pe0_kernel(
    unsigned* t, unsigned* out,
    const float* __restrict__ pe_w, const float* __restrict__ pe_b,
    const float* __restrict__ l0w, const float* __restrict__ l0b) {
  int wid = threadIdx.x >> 6, lane = threadIdx.x & 63;
  size_t token = (size_t)blockIdx.x * 4 + wid;
  unsigned* p = t + token * 64;
  unsigned u = p[lane];
  float vx = bf2f((unsigned short)(u & 0xffff));
  float vy = bf2f((unsigned short)(u >> 16));
  // pe-LN
  float s = vx + vy;
#pragma unroll
  for (int off = 1; off < 64; off <<= 1) s += __shfl_xor(s, off);
  float mu = s * (1.f / 128.f);
  float dx = vx - mu, dy = vy - mu;
  float vs = dx * dx + dy * dy;
#pragma unroll
  for (int off = 1; off < 64; off <<= 1) vs += __shfl_xor(vs, off);
  float r = rsqrtf(vs * (1.f / 128.f) + EPSF);
  float t0 = dx * r * pe_w[lane * 2 + 0] + pe_b[lane * 2 + 0];
  float t1 = dy * r * pe_w[lane * 2 + 1] + pe_b[lane * 2 + 1];
  unsigned short s0 = (unsigned short)f2bf(t0);
  unsigned short s1 = (unsigned short)f2bf(t1);
  p[lane] = (unsigned)s0 | ((unsigned)s1 << 16);
  // block-0 LN on the STORED (rounded) residual values for consistency
  float r0 = bf2f(s0), r1 = bf2f(s1);
  float s2 = r0 + r1;
#pragma unroll
  for (int off = 1; off < 64; off <<= 1) s2 += __shfl_xor(s2, off);
  float mu2 = s2 * (1.f / 128.f);
  float d0 = r0 - mu2, d1 = r1 - mu2;
  float vs2 = d0 * d0 + d1 * d1;
#pragma unroll
  for (int off = 1; off < 64; off <<= 1) vs2 += __shfl_xor(vs2, off);
  float r2 = rsqrtf(vs2 * (1.f / 128.f) + EPSF);
  unsigned lo = (unsigned short)f2bf(d0 * r2 * l0w[lane * 2 + 0] + l0b[lane * 2 + 0]);
  unsigned hi = (unsigned short)f2bf(d1 * r2 * l0w[lane * 2 + 1] + l0b[lane * 2 + 1]);
  out[token * 64 + lane] = lo | (hi << 16);
}

// ---------------- chunked SSM scan, 4 heads/block; conv+dt fused; S shared 4-way ----------------
// grid = 512; b = bid&255, hq = bid>>8 (heads 4hq..4hq+3). 256 threads (4 waves).
// B/C conv+staging and S = C@B^T computed ONCE per block (shared by 4 heads).
// All four P matrices written at once (P0->Cb, P1->Bb, P2->BbT, P3->Pb) after bar2;
// one merged PV pass. 4 barriers per chunk (was 6). LDS 75 KB -> 2 blocks/CU.
__global__ __launch_bounds__(256, 2) void scan_chunk_kernel(
    const unsigned short* __restrict__ zx,   // [T][648] bf16 (cols 256.. = pre-conv xbc)
    const float* __restrict__ dtraw,         // [T][8] fp32
    const float* __restrict__ dtb,           // [8]
    const float* __restrict__ A_log,         // [8]
    const float* __restrict__ cw,            // [384][4] conv weights
    const float* __restrict__ cbv_g,         // [384] conv bias
    const float* __restrict__ Dp,            // [8]
    unsigned short* __restrict__ ysc) {      // [T][256] bf16
  const int b = blockIdx.x & 255, hq = blockIdx.x >> 8;
  const int h0 = hq * 4;
  const int tid = threadIdx.x;
  const int w = tid >> 6, lane = tid & 63;
  const int lr = lane & 15, lj = lane >> 4;
  __shared__ __align__(16) unsigned short Cb[64][72];    // C rows; P0 after bar2
  __shared__ __align__(16) unsigned short Bb[64][72];    // B rows; P1 after bar2
  __shared__ __align__(16) unsigned short BbT[64][72];   // [n][s]; P2 after bar2
  __shared__ __align__(16) unsigned short Pb[64][72];    // P3
  __shared__ __align__(16) unsigned short xT[4][32][72]; // per-head x [p][t]
  __shared__ __align__(16) unsigned short hbT[4][32][72];// per-head h [p][n]
  __shared__ float la[4][64], dtc[4][64], wt[4][64];
  for (int i = tid; i < 4608; i += 256) ((unsigned*)hbT)[i] = 0;
  f32x4 acc_h[8] = {};    // wave w: head w, rows rh*16.. (rh = frag>>2), cols ni*16..
  const float dp0 = Dp[h0], dp1 = Dp[h0 + 1], dp2 = Dp[h0 + 2], dp3 = Dp[h0 + 3];
  __syncthreads();

  for (int c = 0; c < 4; ++c) {
    const int tok0 = b * 256 + c * 64;
    // ---- dt + prefix-scan: wave w -> head h0+w ----
    {
      int hh = h0 + w;
      float raw = dtraw[(size_t)(tok0 + lane) * 8 + hh] + dtb[hh];
      float dt = raw > 20.f ? raw : log1pf(expf(raw));
      float v = -expf(A_log[hh]) * dt;
#pragma unroll
      for (int off = 1; off < 64; off <<= 1) {
        float u = __shfl_up(v, off);
        if (lane >= off) v += u;
      }
      la[w][lane] = v;
      dtc[w][lane] = dt;
    }
    // ---- staging with fused conv1d + SiLU: 256 x-items (4 heads) + 128 B + 128 C ----
    for (int it = tid; it < 512; it += 256) {
      int t0, ch, kind, sub;
      if (it < 256) {
        int hx = it >> 6, id = it & 63;
        t0 = (id >> 2) * 4; sub = (id & 3) * 8;
        ch = (h0 + hx) * 32 + sub; kind = hx;
      } else if (it < 384) {
        int id = it - 256;
        t0 = (id >> 3) * 4; sub = (id & 7) * 8;
        ch = 256 + sub; kind = 4;
      } else {
        int id = it - 384;
        t0 = (id >> 3) * 4; sub = (id & 7) * 8;
        ch = 320 + sub; kind = 5;
      }
      const unsigned short* zp = zx + (size_t)(tok0 + t0) * DIN + 256 + ch;
      const int t0loc = c * 64 + t0;
      short8 rr[7];
      if (t0loc >= 3) {
#pragma unroll
        for (int d = 0; d < 7; ++d)
          rr[d] = *(const short8*)(zp + (ptrdiff_t)(d - 3) * DIN);
      } else {
#pragma unroll
        for (int d = 0; d < 7; ++d) {
          short8 z8 = {};
          if (t0loc + d - 3 >= 0) z8 = *(const short8*)(zp + (ptrdiff_t)(d - 3) * DIN);
          rr[d] = z8;
        }
      }
      float4 cwv[8];
      float cbl[8];
#pragma unroll
      for (int j = 0; j < 8; ++j) {
        cwv[j] = *(const float4*)(cw + (ch + j) * 4);
        cbl[j] = cbv_g[ch + j];
      }
      short8 o[4];
#pragma unroll
      for (int tt = 0; tt < 4; ++tt) {
#pragma unroll
        for (int j = 0; j < 8; ++j) {
          float a = cbl[j]
                  + cwv[j].x * bf2f((unsigned short)rr[tt + 0][j])
                  + cwv[j].y * bf2f((unsigned short)rr[tt + 1][j])
                  + cwv[j].z * bf2f((unsigned short)rr[tt + 2][j])
                  + cwv[j].w * bf2f((unsigned short)rr[tt + 3][j]);
          o[tt][j] = f2bf(fast_silu(a));
        }
      }
      if (kind < 4) {
#pragma unroll
        for (int j = 0; j < 8; ++j) {
          ushort4 v;
          v.x = (unsigned short)o[0][j]; v.y = (unsigned short)o[1][j];
          v.z = (unsigned short)o[2][j]; v.w = (unsigned short)o[3][j];
          *(ushort4*)&xT[kind][sub + j][t0] = v;
        }
      } else if (kind == 4) {
        *(short8*)&Bb[t0 + 0][sub] = o[0];
        *(short8*)&Bb[t0 + 1][sub] = o[1];
        *(short8*)&Bb[t0 + 2][sub] = o[2];
        *(short8*)&Bb[t0 + 3][sub] = o[3];
#pragma unroll
        for (int j = 0; j < 8; ++j) {
          ushort4 v;
          v.x = (unsigned short)o[0][j]; v.y = (unsigned short)o[1][j];
          v.z = (unsigned short)o[2][j]; v.w = (unsigned short)o[3][j];
          *(ushort4*)&BbT[sub + j][t0] = v;
        }
      } else {
        *(short8*)&Cb[t0 + 0][sub] = o[0];
        *(short8*)&Cb[t0 + 1][sub] = o[1];
        *(short8*)&Cb[t0 + 2][sub] = o[2];
        *(short8*)&Cb[t0 + 3][sub] = o[3];
      }
    }
    __syncthreads();   // bar1
    wt[w][lane] = __expf(la[w][63] - la[w][lane]) * dtc[w][lane];   // own-wave use only
    // ---- phase1: S = C@B^T (shared), y_inter for 4 heads ----
    short8 afC0 = *(const short8*)&Cb[w * 16 + lr][lj * 8];
    short8 afC1 = *(const short8*)&Cb[w * 16 + lr][32 + lj * 8];
    f32x4 acc_s[4] = {};
#pragma unroll
    for (int ni = 0; ni < 4; ++ni) {
      short8 bf0 = *(const short8*)&Bb[ni * 16 + lr][lj * 8];
      short8 bf1 = *(const short8*)&Bb[ni * 16 + lr][32 + lj * 8];
      acc_s[ni] = __builtin_amdgcn_mfma_f32_16x16x32_bf16(afC0, bf0, acc_s[ni], 0, 0, 0);
      acc_s[ni] = __builtin_amdgcn_mfma_f32_16x16x32_bf16(afC1, bf1, acc_s[ni], 0, 0, 0);
    }
    f32x4 acc_y[4][2] = {};
#pragma unroll
    for (int hh = 0; hh < 4; ++hh) {
#pragma unroll
      for (int ni = 0; ni < 2; ++ni) {
        short8 hf0 = *(const short8*)&hbT[hh][ni * 16 + lr][lj * 8];
        short8 hf1 = *(const short8*)&hbT[hh][ni * 16 + lr][32 + lj * 8];
        acc_y[hh][ni] = __builtin_amdgcn_mfma_f32_16x16x32_bf16(afC0, hf0, acc_y[hh][ni], 0, 0, 0);
        acc_y[hh][ni] = __builtin_amdgcn_mfma_f32_16x16x32_bf16(afC1, hf1, acc_y[hh][ni], 0, 0, 0);
      }
    }
#pragma unroll
    for (int j = 0; j < 4; ++j) {
      int t = w * 16 + lj * 4 + j;
#pragma unroll
      for (int hh = 0; hh < 4; ++hh) {
        float at = __expf(la[hh][t]);
        acc_y[hh][0][j] *= at;
        acc_y[hh][1][j] *= at;
      }
    }
    // ---- h-update: wave w -> head w, full 32 rows (reads BbT, xT[w], wt[w]) ----
    {
      float aend = __expf(la[w][63]);
#pragma unroll
      for (int f = 0; f < 8; ++f)
#pragma unroll
        for (int j = 0; j < 4; ++j) acc_h[f][j] *= aend;
#pragma unroll
      for (int kk = 0; kk < 2; ++kk) {
#pragma unroll
        for (int rh = 0; rh < 2; ++rh) {
          short8 xv = *(const short8*)&xT[w][rh * 16 + lr][kk * 32 + lj * 8];
          short8 axf;
#pragma unroll
          for (int j = 0; j < 8; ++j)
            axf[j] = f2bf(bf2f((unsigned short)xv[j]) * wt[w][kk * 32 + lj * 8 + j]);
#pragma unroll
          for (int ni = 0; ni < 4; ++ni) {
            short8 bw = *(const short8*)&BbT[ni * 16 + lr][kk * 32 + lj * 8];
            acc_h[rh * 4 + ni] = __builtin_amdgcn_mfma_f32_16x16x32_bf16(axf, bw, acc_h[rh * 4 + ni], 0, 0, 0);
          }
        }
      }
    }
    __syncthreads();   // bar2: all Cb/Bb/BbT/hbT reads done
    // ---- P all 4 heads at once: P0->Cb, P1->Bb, P2->BbT, P3->Pb ----
#pragma unroll
    for (int ni = 0; ni < 4; ++ni) {
      int s = ni * 16 + lr;
      float las0 = la[0][s], dts0 = dtc[0][s];
      float las1 = la[1][s], dts1 = dtc[1][s];
      float las2 = la[2][s], dts2 = dtc[2][s];
      float las3 = la[3][s], dts3 = dtc[3][s];
#pragma unroll
      for (int j = 0; j < 4; ++j) {
        int t = w * 16 + lj * 4 + j;
        float pv0 = 0.f, pv1 = 0.f, pv2 = 0.f, pv3 = 0.f;
        if (s <= t) {
          float sv = acc_s[ni][j];
          pv0 = sv * __expf(la[0][t] - las0) * dts0;
          pv1 = sv * __expf(la[1][t] - las1) * dts1;
          pv2 = sv * __expf(la[2][t] - las2) * dts2;
          pv3 = sv * __expf(la[3][t] - las3) * dts3;
        }
        Cb[t][s]  = (unsigned short)f2bf(pv0);
        Bb[t][s]  = (unsigned short)f2bf(pv1);
        BbT[t][s] = (unsigned short)f2bf(pv2);
        Pb[t][s]  = (unsigned short)f2bf(pv3);
      }
    }
    __syncthreads();   // bar3
    // ---- merged PV (all 4 heads) + y epilogue ----
    {
      short8 aP0a = *(const short8*)&Cb[w * 16 + lr][lj * 8];
      short8 aP0b = *(const short8*)&Cb[w * 16 + lr][32 + lj * 8];
      short8 aP1a = *(const short8*)&Bb[w * 16 + lr][lj * 8];
      short8 aP1b = *(const short8*)&Bb[w * 16 + lr][32 + lj * 8];
      short8 aP2a = *(const short8*)&BbT[w * 16 + lr][lj * 8];
      short8 aP2b = *(const short8*)&BbT[w * 16 + lr][32 + lj * 8];
      short8 aP3a = *(const short8*)&Pb[w * 16 + lr][lj * 8];
      short8 aP3b = *(const short8*)&Pb[w * 16 + lr][32 + lj * 8];
#pragma unroll
      for (int ni = 0; ni < 2; ++ni) {
        short8 x0a = *(const short8*)&xT[0][ni * 16 + lr][lj * 8];
        short8 x0b = *(const short8*)&xT[0][ni * 16 + lr][32 + lj * 8];
        acc_y[0][ni] = __builtin_amdgcn_mfma_f32_16x16x32_bf16(aP0a, x0a, acc_y[0][ni], 0, 0, 0);
        acc_y[0][ni] = __builtin_amdgcn_mfma_f32_16x16x32_bf16(aP0b, x0b, acc_y[0][ni], 0, 0, 0);
        short8 x1a = *(const short8*)&xT[1][ni * 16 + lr][lj * 8];
        short8 x1b = *(const short8*)&xT[1][ni * 16 + lr][32 + lj * 8];
        acc_y[1][ni] = __builtin_amdgcn_mfma_f32_16x16x32_bf16(aP1a, x1a, acc_y[1][ni], 0, 0, 0);
        acc_y[1][ni] = __builtin_amdgcn_mfma_f32_16x16x32_bf16(aP1b, x1b, acc_y[1][ni], 0, 0, 0);
        short8 x2a = *(const short8*)&xT[2][ni * 16 + lr][lj * 8];
        short8 x2b = *(const short8*)&xT[2][ni * 16 + lr][32 + lj * 8];
        acc_y[2][ni] = __builtin_amdgcn_mfma_f32_16x16x32_bf16(aP2a, x2a, acc_y[2][ni], 0, 0, 0);
        acc_y[2][ni] = __builtin_amdgcn_mfma_f32_16x16x32_bf16(aP2b, x2b, acc_y[2][ni], 0, 0, 0);
        short8 x3a = *(const short8*)&xT[3][ni * 16 + lr][lj * 8];
        short8 x3b = *(const short8*)&xT[3][ni * 16 + lr][32 + lj * 8];
        acc_y[3][ni] = __builtin_amdgcn_mfma_f32_16x16x32_bf16(aP3a, x3a, acc_y[3][ni], 0, 0, 0);
        acc_y[3][ni] = __builtin_amdgcn_mfma_f32_16x16x32_bf16(aP3b, x3b, acc_y[3][ni], 0, 0, 0);
      }
#pragma unroll
      for (int ni = 0; ni < 2; ++ni) {
#pragma unroll
        for (int j = 0; j < 4; ++j) {
          int t = w * 16 + lj * 4 + j;
          int p = ni * 16 + lr;
          size_t base = (size_t)(tok0 + t) * DI;
          float yv0 = acc_y[0][ni][j] + dp0 * bf2f(xT[0][p][t]);
          ysc[base + (h0 + 0) * 32 + p] = (unsigned short)f2bf(yv0);
          float yv1 = acc_y[1][ni][j] + dp1 * bf2f(xT[1][p][t]);
          ysc[base + (h0 + 1) * 32 + p] = (unsigned short)f2bf(yv1);
          float yv2 = acc_y[2][ni][j] + dp2 * bf2f(xT[2][p][t]);
          ysc[base + (h0 + 2) * 32 + p] = (unsigned short)f2bf(yv2);
          float yv3 = acc_y[3][ni][j] + dp3 * bf2f(xT[3][p][t]);
          ysc[base + (h0 + 3) * 32 + p] = (unsigned short)f2bf(yv3);
        }
      }
    }
    // ---- h writeback: wave w -> hbT[w], 32 rows (hbT reads all done in phase1) ----
#pragma unroll
    for (int rh = 0; rh < 2; ++rh)
#pragma unroll
      for (int ni = 0; ni < 4; ++ni)
#pragma unroll
        for (int j = 0; j < 4; ++j)
          hbT[w][rh * 16 + lj * 4 + j][ni * 16 + lr] = (unsigned short)f2bf(acc_h[rh * 4 + ni][j]);
    __syncthreads();   // bar4
  }
}

// ---------------- head: column mean + matmul + L2 normalize (fused) ----------------
__global__ __launch_bounds__(128) void head_kernel(
    const unsigned short* __restrict__ tn, const float* __restrict__ hw,
    const float* __restrict__ hb, float* __restrict__ out) {
  __shared__ float tm[128];
  __shared__ float red[2];
  int b = blockIdx.x, o = threadIdx.x;
  {
    const unsigned short* p = tn + (size_t)b * 256 * 128 + o;
    float acc = 0.f;
    for (int l = 0; l < 256; ++l) acc += bf2f(p[l * 128]);
    tm[o] = acc * (1.f / 256.f);
  }
  __syncthreads();
  float acc = hb[o];
  for (int e = 0; e < 128; ++e) acc += tm[e] * hw[o * 128 + e];
  float ss = acc * acc;
#pragma unroll
  for (int off = 1; off < 64; off <<= 1) ss += __shfl_xor(ss, off);
  if ((o & 63) == 0) red[o >> 6] = ss;
  __syncthreads();
  float nrm = fmaxf(sqrtf(red[0] + red[1]), 1e-12f);
  out[b * 128 + o] = acc / nrm;
}

extern "C" void kernel_launch(void* const* d_in, const int* in_sizes, int n_in,
                              void* d_out, int out_size, void* d_ws, size_t ws_size,
                              hipStream_t stream) {
  const float* x      = (const float*)d_in[0];
  const float* conv_w = (const float*)d_in[1];
  const float* conv_b = (const float*)d_in[2];
  const float* pe_w   = (const float*)d_in[3];
  const float* pe_b   = (const float*)d_in[4];
  const float* ln_w   = (const float*)d_in[5];
  const float* ln_b   = (const float*)d_in[6];
  const float* in_w   = (const float*)d_in[7];
  const float* c1w    = (const float*)d_in[8];
  const float* c1b    = (const float*)d_in[9];
  const float* dtb    = (const float*)d_in[10];
  const float* A_log  = (const float*)d_in[11];
  const float* Dp     = (const float*)d_in[12];
  const float* nw     = (const float*)d_in[13];
  const float* ow     = (const float*)d_in[14];
  const float* fn_w   = (const float*)d_in[15];
  const float* fn_b   = (const float*)d_in[16];
  const float* hw     = (const float*)d_in[17];
  const float* hb     = (const float*)d_in[18];
  float* out = (float*)d_out;

  const size_t T = TTOK;
  char* w8 = (char*)d_ws;
  unsigned short* t_buf = (unsigned short*)w8;   w8 += T * 128 * 2;   // residual bf16
  unsigned*       tnb   = (unsigned*)w8;         w8 += T * 128 * 2;   // ln out bf16
  unsigned short* zx    = (unsigned short*)w8;   w8 += T * (size_t)DIN * 2; // in-proj bf16
  float*          dtraw = (float*)w8;            w8 += T * 8 * 4;
  unsigned short* ysc   = (unsigned short*)w8;   w8 += T * (size_t)DI * 2;  // scan out bf16
  unsigned short* in_wb = (unsigned short*)w8;   w8 += (size_t)NL * DIN * EE * 2;
  unsigned short* owb   = (unsigned short*)w8;   w8 += (size_t)NL * EE * DI * 2;
  if ((size_t)(w8 - (char*)d_ws) > ws_size) return;  // workspace too small

  // one-shot weight conversion (NL*DIN*EE = 331776 = 1296*256)
  cvt_w_kernel<<<1296, 256, 0, stream>>>(in_w, ow, in_wb, owb);

  // patch embed + bias (bf16 residual), then fused pe-LN + block-0 LN
  gemm_bf16_patch<<<dim3(512, 1), 256, 0, stream>>>(x, conv_w, conv_b, t_buf);
  ln_pe0_kernel<<<16384, 256, 0, stream>>>((unsigned*)t_buf, tnb, pe_w, pe_b, ln_w, ln_b);

  for (int i = 0; i < NL; ++i) {
    gemm_in_proj<<<dim3(5, 512), 256, 0, stream>>>(
        (const unsigned short*)tnb, in_wb + (size_t)i * DIN * EE,
        in_wb + (size_t)i * DIN * EE + 640 * 128, zx, dtraw);
    scan_chunk_kernel<<<512, 256, 0, stream>>>(
        zx, dtraw, dtb + i * HH, A_log + i * HH,
        c1w + (size_t)i * XBC * DC, c1b + (size_t)i * XBC, Dp + i * HH, ysc);
    const float* nlw = (i < NL - 1) ? (ln_w + (i + 1) * 128) : fn_w;
    const float* nlb = (i < NL - 1) ? (ln_b + (i + 1) * 128) : fn_b;
    gemm_out_fused_ln<<<512, 256, 0, stream>>>(
        ysc, zx, nw + i * DI, owb + (size_t)i * EE * DI, t_buf, nlw, nlb, tnb);
  }

  // tnb holds final-LN output (fused in last gemm_out_fused_ln)
  head_kernel<<<256, 128, 0, stream>>>((const unsigned short*)tnb, hw, hb, out);
}